// Round 11
// baseline (1262.548 us; speedup 1.0000x reference)
//
#include <hip/hip_runtime.h>
#include <hip/hip_bf16.h>

typedef __bf16 bf16;
typedef __attribute__((ext_vector_type(8))) __bf16 bf16x8;
typedef __attribute__((ext_vector_type(4))) __bf16 bf16x4;
typedef __attribute__((ext_vector_type(4))) float f32x4;

constexpr int BATCH = 8192, NN = 49, ND = 26, NOUT = 1274, FD = 1280;
constexpr int HID = 256, NE = 361, HEADS = 4;
constexpr int KT_X = 40;
constexpr int MT_X = 512;
constexpr int NB_W = 10;
constexpr int NTB  = 9;

// ---- workspace layout (bytes) ----
constexpr size_t OFF_XPACK = 0;
constexpr size_t SZ_XPACK  = (size_t)MT_X * KT_X * 512 * 2;
constexpr size_t OFF_WPACK = OFF_XPACK + SZ_XPACK;
constexpr size_t SZ_WPACK  = (size_t)NB_W * NTB * KT_X * 512 * 2;
constexpr size_t OFF_B1    = OFF_WPACK + SZ_WPACK;
constexpr size_t SZ_B1     = (size_t)32 * 512 * 2;
constexpr size_t OFF_B2    = OFF_B1 + SZ_B1;
constexpr size_t SZ_B2     = (size_t)32 * 8 * 512 * 2;
constexpr size_t OFF_N32   = OFF_B2 + SZ_B2;
constexpr size_t SZ_N32    = (size_t)BATCH * NN * 32 * 2;
constexpr size_t OFF_PN    = OFF_N32 + SZ_N32;
constexpr size_t SZ_PN     = (size_t)BATCH * ND * 4;
constexpr size_t OFF_CSR   = OFF_PN + SZ_PN;
constexpr size_t SZ_CSR    = 8192;
constexpr size_t OFF_CHUNK = OFF_CSR + SZ_CSR;

// csr int layout (slot-ordered):
// [0..49] in-off | [411..771] slot->src | [1200..1560] slot->dst
// [772..821] out-off | [822..1182] out-edge SLOT ids

// ============ K0a: pack x -> A-fragments bf16 ============
__global__ __launch_bounds__(256) void k_pack_x(const float* __restrict__ x,
                                                bf16* __restrict__ xp) {
    int g = blockIdx.x * 256 + threadIdx.x;
    int lane = g & 63, frag = g >> 6;
    int mt = frag / KT_X, kt = frag - mt * KT_X;
    int row = mt * 16 + (lane & 15);
    int k0  = kt * 32 + (lane >> 4) * 8;
    const float* src = x + (size_t)row * FD + k0;
    bf16x8 v;
#pragma unroll
    for (int j = 0; j < 8; ++j) v[j] = (bf16)src[j];
    *(bf16x8*)(xp + ((size_t)frag * 64 + lane) * 8) = v;
}

// ======== K0b: pack transform_w -> B-frags, node-aligned col-blocks ========
__global__ __launch_bounds__(256) void k_pack_w(const float* __restrict__ w,
                                                bf16* __restrict__ wp) {
    int g = blockIdx.x * 256 + threadIdx.x;
    int lane = g & 63, frag = g >> 6;
    int kt = frag % KT_X, t2 = frag / KT_X;
    int nt = t2 % NTB, nb = t2 / NTB;
    int col = nb * 130 + nt * 16 + (lane & 15);
    int k0  = kt * 32 + (lane >> 4) * 8;
    bool ok = (col < NOUT) && (col < nb * 130 + 130);
    bf16x8 v;
#pragma unroll
    for (int j = 0; j < 8; ++j)
        v[j] = ok ? (bf16)w[(size_t)(k0 + j) * NOUT + col] : (bf16)0.f;
    *(bf16x8*)(wp + ((size_t)frag * 64 + lane) * 8) = v;
}

// ============ K0c: pack g1 -> B-fragments ============
__global__ __launch_bounds__(256) void k_pack_g1(const float* __restrict__ wl,
                                                 const float* __restrict__ wr,
                                                 bf16* __restrict__ bp) {
    int g = blockIdx.x * 256 + threadIdx.x;
    int lane = g & 63, nt = g >> 6;
    int n  = nt * 16 + (lane & 15);
    int k0 = (lane >> 4) * 8;
    bf16x8 v;
#pragma unroll
    for (int j = 0; j < 8; ++j) {
        int k = k0 + j;
        float f = 0.f;
        if (k < ND) f = (n < HID) ? wl[k * HID + n] : wr[k * HID + (n - HID)];
        v[j] = (bf16)f;
    }
    *(bf16x8*)(bp + ((size_t)nt * 64 + lane) * 8) = v;
}

// ============ K0d: pack g2 -> B-fragments ============
__global__ __launch_bounds__(256) void k_pack_g2(const float* __restrict__ wl,
                                                 const float* __restrict__ wr,
                                                 bf16* __restrict__ bp) {
    int g = blockIdx.x * 256 + threadIdx.x;
    int lane = g & 63, frag = g >> 6;
    int nt = frag >> 3, kt = frag & 7;
    int n  = nt * 16 + (lane & 15);
    int k0 = kt * 32 + (lane >> 4) * 8;
    bf16x8 v;
#pragma unroll
    for (int j = 0; j < 8; ++j) {
        int k = k0 + j;
        float f = (n < HID) ? wl[k * HID + n] : wr[k * HID + (n - HID)];
        v[j] = (bf16)f;
    }
    *(bf16x8*)(bp + ((size_t)frag * 64 + lane) * 8) = v;
}

// ====== K0e: build slot-ordered CSR (parallel, deterministic) ======
__global__ __launch_bounds__(128) void k_csr_par(const int* __restrict__ ei,
                                                 int* __restrict__ csr) {
    __shared__ int es[NE], ed[NE], cnt[NN], ocnt[NN], off[NN + 1], ooff[NN + 1];
    __shared__ int eslot[NE];
    int tid = threadIdx.x;
    if (tid < NN) { cnt[tid] = 0; ocnt[tid] = 0; }
    for (int e = tid; e < NE; e += 128) { es[e] = ei[e]; ed[e] = ei[NE + e]; }
    __syncthreads();
    for (int e = tid; e < NE; e += 128) {
        atomicAdd(&cnt[ed[e]], 1);
        atomicAdd(&ocnt[es[e]], 1);
    }
    __syncthreads();
    if (tid == 0) {
        off[0] = 0; ooff[0] = 0;
        for (int n = 0; n < NN; ++n) {
            off[n + 1] = off[n] + cnt[n];
            ooff[n + 1] = ooff[n] + ocnt[n];
        }
    }
    __syncthreads();
    if (tid < NN) {                         // in-edge scatter (slot order)
        int p = off[tid];
        for (int e = 0; e < NE; ++e)
            if (ed[e] == tid) {
                csr[411 + p] = es[e];       // slot -> src
                csr[1200 + p] = tid;        // slot -> dst
                eslot[e] = p;
                ++p;
            }
    }
    __syncthreads();
    if (tid < NN) {                         // out-edge scatter -> slot ids
        int p = ooff[tid];
        for (int e = 0; e < NE; ++e)
            if (es[e] == tid) { csr[822 + p] = eslot[e]; ++p; }
    }
    if (tid < 50) { csr[tid] = off[tid]; csr[772 + tid] = ooff[tid]; }
}

// ==== K1: transform GEMM -> node32 [B*49][32] bf16 (4 Mt/wave) ====
__global__ __launch_bounds__(256, 2) void k_gemm_node(const bf16* __restrict__ xp,
                                                      const bf16* __restrict__ wp,
                                                      const float* __restrict__ tb,
                                                      bf16* __restrict__ node32) {
    __shared__ bf16 L[128][148];
    __shared__ float tbS[144];
    int tid = threadIdx.x, lane = tid & 63, w = tid >> 6;
    int nb = blockIdx.y, C0 = nb * 130;
    int mt0 = blockIdx.x * 16 + w * 4;
    if (tid < 144) { int col = C0 + tid; tbS[tid] = (col < NOUT) ? tb[col] : 0.f; }
    f32x4 acc[4][9] = {};
    const bf16* wpB = wp + (size_t)(nb * NTB) * KT_X * 512;
    for (int kt = 0; kt < KT_X; ++kt) {
        bf16x8 a[4];
#pragma unroll
        for (int i = 0; i < 4; ++i)
            a[i] = *(const bf16x8*)(xp + (((size_t)(mt0 + i) * KT_X + kt) * 64 + lane) * 8);
#pragma unroll
        for (int j = 0; j < NTB; ++j) {
            bf16x8 b = *(const bf16x8*)(wpB + ((size_t)(j * KT_X + kt) * 64 + lane) * 8);
#pragma unroll
            for (int i = 0; i < 4; ++i)
                acc[i][j] = __builtin_amdgcn_mfma_f32_16x16x32_bf16(a[i], b, acc[i][j], 0, 0, 0);
        }
    }
    int c0 = lane & 15, r0 = (lane >> 4) * 4;
    int nodes = (nb == 9) ? 4 : 5;
    int total = 128 * nodes * 4;
    for (int half = 0; half < 2; ++half) {
        __syncthreads();
        if ((w >> 1) == half) {
            int lrbase = (w & 1) * 64;
#pragma unroll
            for (int i = 0; i < 4; ++i) {
#pragma unroll
                for (int j = 0; j < NTB; ++j) {
                    int col = j * 16 + c0;
                    float bias = tbS[col];
#pragma unroll
                    for (int r = 0; r < 4; ++r)
                        L[lrbase + i * 16 + r0 + r][col] = (bf16)(acc[i][j][r] + bias);
                }
            }
        }
        __syncthreads();
        int B0 = blockIdx.x * 256 + half * 128;
        for (int t = tid; t < total; t += 256) {
            int q = t & 3, t2 = t >> 2;
            int n_l = t2 % nodes, brow = t2 / nodes;
            bf16x8 o;
#pragma unroll
            for (int jj = 0; jj < 8; ++jj) {
                int d = q * 8 + jj;
                o[jj] = (d < ND) ? L[brow][n_l * 26 + d] : (bf16)0.f;
            }
            *(bf16x8*)(node32 + (((size_t)(B0 + brow) * NN + nb * 5 + n_l) * 32 + q * 8)) = o;
        }
    }
}

// ============ K1b: pooled node features (sum over 49 nodes) ============
__global__ __launch_bounds__(256) void k_pool(const bf16* __restrict__ node32,
                                              float* __restrict__ pN) {
    int b = blockIdx.x * 8 + (threadIdx.x >> 5);
    int d = threadIdx.x & 31;
    if (d >= ND) return;
    const bf16* base = node32 + (size_t)b * NN * 32 + d;
    float s = 0.f;
    for (int n = 0; n < NN; ++n) s += (float)base[n * 32];
    pN[b * ND + d] = s;
}

// ======= K_A: fused layer-1 GEMM (swapped-mfma epilogue) + edge phase 1 ====
__global__ __launch_bounds__(512, 2) void k_fuse1(const bf16* __restrict__ n32,
                                                  const bf16* __restrict__ B1p,
                                                  bf16* __restrict__ h1f,
                                                  const float* __restrict__ att1,
                                                  const float* __restrict__ g1b,
                                                  const int* __restrict__ csr) {
    __shared__ __align__(16) char X[NN * 1024];
    __shared__ __align__(16) float A6S[256], A4S[256];
    __shared__ float sc[NE * 4], srden[NN * 4], bS[256];
    __shared__ int ieOff[50], srcJ[NE], dstJ[NE];

    int tid = threadIdx.x, lane = tid & 63, w = tid >> 6, g = blockIdx.x;

    for (int i = tid; i < 256; i += 512) {
        float a = att1[i];
        A6S[i] = 0.6f * a; A4S[i] = 0.4f * a; bS[i] = g1b[i];
    }
    for (int i = tid; i < NE; i += 512) {
        srcJ[i] = csr[411 + i]; dstJ[i] = csr[1200 + i];
    }
    if (tid < 50) ieOff[tid] = csr[tid];

    // ---- layer-1 GEMM: mfma(Wfrag as A, nodefrag as B) -> X swizzled ----
    {
        int mt = w & 3, ng = w >> 2;
        int m = mt * 16 + (lane & 15);
        bf16x8 bfrag = {};
        if (m < NN)
            bfrag = *(const bf16x8*)(n32 + ((size_t)(g * NN + m) * 32 + (lane >> 4) * 8));
        int chq = (lane >> 4) * 4;
        int sw = (m & 7) << 4;
        char* rowp = X + m * 1024;
#pragma unroll
        for (int j = 0; j < 16; ++j) {
            f32x4 z = {0.f, 0.f, 0.f, 0.f};
            bf16x8 afrag = *(const bf16x8*)(B1p + ((size_t)(ng * 16 + j) * 64 + lane) * 8);
            f32x4 acc = __builtin_amdgcn_mfma_f32_16x16x32_bf16(afrag, bfrag, z, 0, 0, 0);
            if (m < NN) {
                int ch = (ng * 16 + j) * 16 + chq;
                bf16x4 o4;
#pragma unroll
                for (int r = 0; r < 4; ++r) o4[r] = (bf16)acc[r];
                *(bf16x4*)(rowp + ((ch * 2) ^ sw)) = o4;
            }
        }
    }
    __syncthreads();

    // ---- scores (slot-ordered, 2-fma lrelu) ----
    int rot = tid & 7;
    for (int task = tid; task < NE * 4; task += 512) {
        int h = task / NE, j = task - h * NE;
        int s = srcJ[j], d = dstJ[j];
        int sws = (s & 7) << 4, swd = (d & 7) << 4;
        const char* ps = X + s * 1024;
        const char* pd = X + d * 1024;
        float pa0 = 0.f, pa1 = 0.f, pb0 = 0.f, pb1 = 0.f;
#pragma unroll
        for (int i = 0; i < 8; ++i) {
            int cc = ((i + rot) & 7) * 8;
            bf16x8 xl = *(const bf16x8*)(ps + (((h * 64 + cc) * 2) ^ sws));
            bf16x8 xr = *(const bf16x8*)(pd + (((256 + h * 64 + cc) * 2) ^ swd));
            float4 a60 = *(const float4*)(A6S + h * 64 + cc);
            float4 a61 = *(const float4*)(A6S + h * 64 + cc + 4);
            float4 a40 = *(const float4*)(A4S + h * 64 + cc);
            float4 a41 = *(const float4*)(A4S + h * 64 + cc + 4);
            const float a6[8] = {a60.x, a60.y, a60.z, a60.w, a61.x, a61.y, a61.z, a61.w};
            const float a4[8] = {a40.x, a40.y, a40.z, a40.w, a41.x, a41.y, a41.z, a41.w};
#pragma unroll
            for (int q = 0; q < 8; ++q) {
                float v = (float)xl[q] + (float)xr[q];
                if (q & 1) { pa1 = fmaf(a6[q], v, pa1); pb1 = fmaf(a4[q], fabsf(v), pb1); }
                else       { pa0 = fmaf(a6[q], v, pa0); pb0 = fmaf(a4[q], fabsf(v), pb0); }
            }
        }
        sc[j * 4 + h] = (pa0 + pa1) + (pb0 + pb1);
    }
    __syncthreads();
    // ---- softmax stats (linear slots, exp-writeback) ----
    for (int t = tid; t < NN * 4; t += 512) {
        int n = t >> 2, h = t & 3;
        int j0 = ieOff[n], j1 = ieOff[n + 1];
        float m = -1e30f;
        for (int j = j0; j < j1; ++j) m = fmaxf(m, sc[j * 4 + h]);
        float den = 0.f;
        for (int j = j0; j < j1; ++j) {
            float ex = __expf(sc[j * 4 + h] - m);
            sc[j * 4 + h] = ex; den += ex;
        }
        srden[t] = 1.f / den;
    }
    __syncthreads();
    // ---- aggregate (linear slots) + bias + ELU -> h1 fragments ----
    for (int task = tid; task < NN * 32; task += 512) {
        int n = task >> 5, cb = task & 31;
        int ch0 = cb * 8, hh = cb >> 3;
        float a8[8] = {};
        int j0 = ieOff[n], j1 = ieOff[n + 1];
        for (int j = j0; j < j1; ++j) {
            float al = sc[j * 4 + hh];
            int s = srcJ[j];
            bf16x8 xv = *(const bf16x8*)(X + s * 1024 + ((ch0 * 2) ^ ((s & 7) << 4)));
#pragma unroll
            for (int q = 0; q < 8; ++q) a8[q] = fmaf(al, (float)xv[q], a8[q]);
        }
        float rs = srden[n * 4 + hh];
        bf16x8 o;
#pragma unroll
        for (int q = 0; q < 8; ++q) {
            float v = fmaf(a8[q], rs, bS[ch0 + q]);
            v = v > 0.f ? v : (__expf(v) - 1.f);
            o[q] = (bf16)v;
        }
        int Rl = g * NN + n;
        int kt = ch0 >> 5, kg = (ch0 >> 3) & 3;
        size_t addr = (((size_t)(Rl >> 4) * 8 + kt) * 64 + (Rl & 15) + 16 * kg) * 8;
        *(bf16x8*)(h1f + addr) = o;
    }
}

// ==== K_B1: batched layer-2 GEMM (h1 frags -> LINEAR row-major xlr) ========
__global__ __launch_bounds__(256) void k_gemm_l2(const bf16* __restrict__ Af,
                                                 const bf16* __restrict__ Bf,
                                                 bf16* __restrict__ xlr) {
    __shared__ bf16 LT[128][136];
    int tid = threadIdx.x, lane = tid & 63, w = tid >> 6;
    int mtb = blockIdx.x * 8 + (w >> 1) * 4;
    int ntb = blockIdx.y * 8 + (w & 1) * 4;
    f32x4 acc[4][4] = {};
    for (int kt = 0; kt < 8; ++kt) {
        bf16x8 a[4], b[4];
#pragma unroll
        for (int i = 0; i < 4; ++i)
            a[i] = *(const bf16x8*)(Af + (((size_t)(mtb + i) * 8 + kt) * 64 + lane) * 8);
#pragma unroll
        for (int j = 0; j < 4; ++j)
            b[j] = *(const bf16x8*)(Bf + (((size_t)(ntb + j) * 8 + kt) * 64 + lane) * 8);
#pragma unroll
        for (int i = 0; i < 4; ++i)
#pragma unroll
            for (int j = 0; j < 4; ++j)
                acc[i][j] = __builtin_amdgcn_mfma_f32_16x16x32_bf16(a[i], b[j], acc[i][j], 0, 0, 0);
    }
    int c0 = lane & 15, r0 = (lane >> 4) * 4;
    int lr0 = (w >> 1) * 64, lc0 = (w & 1) * 64;
#pragma unroll
    for (int i = 0; i < 4; ++i)
#pragma unroll
        for (int j = 0; j < 4; ++j)
#pragma unroll
            for (int r = 0; r < 4; ++r)
                LT[lr0 + i * 16 + r0 + r][lc0 + j * 16 + c0] = (bf16)acc[i][j][r];
    __syncthreads();
    size_t R0 = (size_t)blockIdx.x * 128, C0 = (size_t)blockIdx.y * 128;
#pragma unroll
    for (int it = 0; it < 8; ++it) {
        int idx = (it * 256 + tid) * 8;
        int r = idx >> 7, c = idx & 127;
        bf16x8 v = *(const bf16x8*)&LT[r][c];
        *(bf16x8*)(xlr + (R0 + r) * 512 + C0 + c) = v;
    }
}

// == K_B2: scores + softmax + wN + pooled g + FC, one X stage (block/graph) =
static __device__ __forceinline__ float waveReduceSum(float v) {
#pragma unroll
    for (int m = 32; m > 0; m >>= 1) v += __shfl_xor(v, m, 64);
    return v;
}

__global__ __launch_bounds__(384, 2) void k_post2(const bf16* __restrict__ xlr,
                                                  const float* __restrict__ att2,
                                                  const float* __restrict__ pN,
                                                  const float* __restrict__ g2b,
                                                  const float* __restrict__ fcw,
                                                  const float* __restrict__ fcb,
                                                  const int* __restrict__ csr,
                                                  int graph_base,
                                                  float* __restrict__ out) {
    __shared__ __align__(16) char X[NN * 1024];
    __shared__ float A6S[256], A4S[256];
    __shared__ float sc[NE], sm[NN], sr[NN], wS[NN];
    __shared__ float poolS[288];
    __shared__ int srcJ[NE], dstJ[NE], oSlot[NE], inOff[50], oOff[50];
    int tid = threadIdx.x, g = blockIdx.x;
    const char* srcp = (const char*)(xlr + (size_t)g * NN * 512);
    for (int off = tid * 16; off < NN * 1024; off += 384 * 16) {
        int row = off >> 10;
        *(uint4*)(X + (off ^ ((row & 7) << 4))) = *(const uint4*)(srcp + off);
    }
    if (tid < 256) { float a = att2[tid]; A6S[tid] = 0.6f * a; A4S[tid] = 0.4f * a; }
    if (tid >= 256 && tid < 256 + ND)
        poolS[tid - 256] = pN[(size_t)(graph_base + g) * ND + (tid - 256)] * (1.f / NN);
    for (int i = tid; i < NE; i += 384) {
        srcJ[i] = csr[411 + i]; dstJ[i] = csr[1200 + i]; oSlot[i] = csr[822 + i];
    }
    if (tid < 50) { inOff[tid] = csr[tid]; oOff[tid] = csr[772 + tid]; }
    __syncthreads();
    // ---- scores (slot per thread, 2-fma lrelu) ----
    if (tid < NE) {
        int s = srcJ[tid], d = dstJ[tid];
        int sws = (s & 7) << 4, swd = (d & 7) << 4;
        const char* ps = X + s * 1024;
        const char* pd = X + d * 1024;
        int rot = tid & 7;
        float pa0 = 0.f, pa1 = 0.f, pb0 = 0.f, pb1 = 0.f;
#pragma unroll 8
        for (int i = 0; i < 32; ++i) {
            int cc = ((i + rot) & 31) * 8;
            bf16x8 xl = *(const bf16x8*)(ps + ((cc * 2) ^ sws));
            bf16x8 xr = *(const bf16x8*)(pd + (((256 + cc) * 2) ^ swd));
            float4 a60 = *(const float4*)(A6S + cc);
            float4 a61 = *(const float4*)(A6S + cc + 4);
            float4 a40 = *(const float4*)(A4S + cc);
            float4 a41 = *(const float4*)(A4S + cc + 4);
            const float a6[8] = {a60.x, a60.y, a60.z, a60.w, a61.x, a61.y, a61.z, a61.w};
            const float a4[8] = {a40.x, a40.y, a40.z, a40.w, a41.x, a41.y, a41.z, a41.w};
#pragma unroll
            for (int q = 0; q < 8; ++q) {
                float v = (float)xl[q] + (float)xr[q];
                if (q & 1) { pa1 = fmaf(a6[q], v, pa1); pb1 = fmaf(a4[q], fabsf(v), pb1); }
                else       { pa0 = fmaf(a6[q], v, pa0); pb0 = fmaf(a4[q], fabsf(v), pb0); }
            }
        }
        sc[tid] = (pa0 + pa1) + (pb0 + pb1);
    }
    __syncthreads();
    // ---- softmax stats (linear slots) ----
    if (tid < NN) {
        int j0 = inOff[tid], j1 = inOff[tid + 1];
        float m = -1e30f;
        for (int j = j0; j < j1; ++j) m = fmaxf(m, sc[j]);
        float den = 0.f;
        for (int j = j0; j < j1; ++j) den += __expf(sc[j] - m);
        sm[tid] = m; sr[tid] = 1.f / den;
    }
    __syncthreads();
    // ---- out-node alpha sums (via out-edge slots) ----
    if (tid < NN) {
        float wa = 0.f;
        int j0 = oOff[tid], j1 = oOff[tid + 1];
        for (int j = j0; j < j1; ++j) {
            int slot = oSlot[j];
            int d = dstJ[slot];
            wa += __expf(sc[slot] - sm[d]) * sr[d];
        }
        wS[tid] = wa;
    }
    __syncthreads();
    // ---- pooled g from LDS ----
    if (tid < HID) {
        float acc = 0.f;
#pragma unroll
        for (int n = 0; n < NN; ++n) {
            float v = (float)*(const bf16*)(X + n * 1024 + ((tid * 2) ^ ((n & 7) << 4)));
            acc = fmaf(wS[n], v, acc);
        }
        poolS[ND + tid] = acc * (1.f / NN) + g2b[tid];
    }
    __syncthreads();
    // ---- FC ----
    int w5 = tid >> 6, lane = tid & 63;
    if (w5 < 5) {
        float a = 0.f;
        for (int d = lane; d < ND + HID; d += 64) a = fmaf(poolS[d], fcw[d * 5 + w5], a);
        a = waveReduceSum(a);
        if (lane == 0) out[(size_t)(graph_base + g) * 5 + w5] = a + fcb[w5];
    }
}

// ============ launch ============
extern "C" void kernel_launch(void* const* d_in, const int* in_sizes, int n_in,
                              void* d_out, int out_size, void* d_ws, size_t ws_size,
                              hipStream_t stream) {
    const float* x   = (const float*)d_in[0];
    const float* tw  = (const float*)d_in[1];
    const float* tb  = (const float*)d_in[2];
    const float* wl1 = (const float*)d_in[3];
    const float* wr1 = (const float*)d_in[4];
    const float* at1 = (const float*)d_in[5];
    const float* b1  = (const float*)d_in[6];
    const float* wl2 = (const float*)d_in[7];
    const float* wr2 = (const float*)d_in[8];
    const float* at2 = (const float*)d_in[9];
    const float* b2  = (const float*)d_in[10];
    const float* fcw = (const float*)d_in[11];
    const float* fcb = (const float*)d_in[12];
    const int*   ei  = (const int*)d_in[13];
    float* out = (float*)d_out;

    char* ws = (char*)d_ws;
    bf16*  xp   = (bf16*)(ws + OFF_XPACK);
    bf16*  wp   = (bf16*)(ws + OFF_WPACK);
    bf16*  b1p  = (bf16*)(ws + OFF_B1);
    bf16*  b2p  = (bf16*)(ws + OFF_B2);
    bf16*  n32  = (bf16*)(ws + OFF_N32);
    float* pN   = (float*)(ws + OFF_PN);
    int*   csr  = (int*)(ws + OFF_CSR);

    // chunk buffers: xlr C*50176 B ; h1f C*12544 B
    const size_t perC = 50176 + 12544;
    int C = 512;
    for (int cand : {2048, 1024, 512}) {
        if (OFF_CHUNK + (size_t)cand * perC <= ws_size) { C = cand; break; }
    }
    bf16*  xlr = (bf16*)(ws + OFF_CHUNK);
    bf16*  h1f = (bf16*)(ws + OFF_CHUNK + (size_t)C * 50176);
    int nchunks = BATCH / C;
    int MtC = C * NN / 16;

    k_pack_x<<<dim3(MT_X * KT_X * 64 / 256), dim3(256), 0, stream>>>(x, xp);
    k_pack_w<<<dim3(NB_W * NTB * KT_X * 64 / 256), dim3(256), 0, stream>>>(tw, wp);
    k_pack_g1<<<dim3(8), dim3(256), 0, stream>>>(wl1, wr1, b1p);
    k_pack_g2<<<dim3(64), dim3(256), 0, stream>>>(wl2, wr2, b2p);
    k_csr_par<<<dim3(1), dim3(128), 0, stream>>>(ei, csr);
    k_gemm_node<<<dim3(32, NB_W), dim3(256), 0, stream>>>(xp, wp, tb, n32);
    k_pool<<<dim3(BATCH / 8), dim3(256), 0, stream>>>(n32, pN);

    for (int c = 0; c < nchunks; ++c) {
        const bf16* n32c = n32 + (size_t)c * C * NN * 32;
        k_fuse1<<<dim3(C), dim3(512), 0, stream>>>(n32c, b1p, h1f, at1, b1, csr);
        k_gemm_l2<<<dim3(MtC / 8, 4), dim3(256), 0, stream>>>(h1f, b2p, xlr);
        k_post2<<<dim3(C), dim3(384), 0, stream>>>(xlr, at2, pN, b2, fcw, fcb,
                                                   csr, c * C, out);
    }
}

// Round 12
// 962.595 us; speedup vs baseline: 1.3116x; 1.3116x over previous
//
#include <hip/hip_runtime.h>
#include <hip/hip_bf16.h>

typedef __bf16 bf16;
typedef __attribute__((ext_vector_type(8))) __bf16 bf16x8;
typedef __attribute__((ext_vector_type(4))) __bf16 bf16x4;
typedef __attribute__((ext_vector_type(4))) float f32x4;

constexpr int BATCH = 8192, NN = 49, ND = 26, NOUT = 1274, FD = 1280;
constexpr int HID = 256, NE = 361, HEADS = 4;
constexpr int KT_X = 40;
constexpr int MT_X = 512;
constexpr int NB_W = 10;
constexpr int NTB  = 9;

// ---- workspace layout (bytes) ----
constexpr size_t OFF_XPACK = 0;
constexpr size_t SZ_XPACK  = (size_t)MT_X * KT_X * 512 * 2;
constexpr size_t OFF_WPACK = OFF_XPACK + SZ_XPACK;
constexpr size_t SZ_WPACK  = (size_t)NB_W * NTB * KT_X * 512 * 2;
constexpr size_t OFF_B1    = OFF_WPACK + SZ_WPACK;
constexpr size_t SZ_B1     = (size_t)32 * 512 * 2;
constexpr size_t OFF_B2    = OFF_B1 + SZ_B1;
constexpr size_t SZ_B2     = (size_t)32 * 8 * 512 * 2;
constexpr size_t OFF_N32   = OFF_B2 + SZ_B2;
constexpr size_t SZ_N32    = (size_t)BATCH * NN * 32 * 2;
constexpr size_t OFF_PN    = OFF_N32 + SZ_N32;
constexpr size_t SZ_PN     = (size_t)BATCH * ND * 4;
constexpr size_t OFF_CSR   = OFF_PN + SZ_PN;
constexpr size_t SZ_CSR    = 8192;
constexpr size_t OFF_CHUNK = OFF_CSR + SZ_CSR;

// csr int layout: [0..49] in-off | [50..410] in-edge id | [411..771] in-edge src
//                 [772..821] out-off | [822..1182] out-edge id

// ============ K0a: pack x -> A-fragments bf16 ============
__global__ __launch_bounds__(256) void k_pack_x(const float* __restrict__ x,
                                                bf16* __restrict__ xp) {
    int g = blockIdx.x * 256 + threadIdx.x;
    int lane = g & 63, frag = g >> 6;
    int mt = frag / KT_X, kt = frag - mt * KT_X;
    int row = mt * 16 + (lane & 15);
    int k0  = kt * 32 + (lane >> 4) * 8;
    const float* src = x + (size_t)row * FD + k0;
    bf16x8 v;
#pragma unroll
    for (int j = 0; j < 8; ++j) v[j] = (bf16)src[j];
    *(bf16x8*)(xp + ((size_t)frag * 64 + lane) * 8) = v;
}

// ======== K0b: pack transform_w -> B-frags, node-aligned col-blocks ========
__global__ __launch_bounds__(256) void k_pack_w(const float* __restrict__ w,
                                                bf16* __restrict__ wp) {
    int g = blockIdx.x * 256 + threadIdx.x;
    int lane = g & 63, frag = g >> 6;
    int kt = frag % KT_X, t2 = frag / KT_X;
    int nt = t2 % NTB, nb = t2 / NTB;
    int col = nb * 130 + nt * 16 + (lane & 15);
    int k0  = kt * 32 + (lane >> 4) * 8;
    bool ok = (col < NOUT) && (col < nb * 130 + 130);
    bf16x8 v;
#pragma unroll
    for (int j = 0; j < 8; ++j)
        v[j] = ok ? (bf16)w[(size_t)(k0 + j) * NOUT + col] : (bf16)0.f;
    *(bf16x8*)(wp + ((size_t)frag * 64 + lane) * 8) = v;
}

// ============ K0c: pack g1 -> B-fragments ============
__global__ __launch_bounds__(256) void k_pack_g1(const float* __restrict__ wl,
                                                 const float* __restrict__ wr,
                                                 bf16* __restrict__ bp) {
    int g = blockIdx.x * 256 + threadIdx.x;
    int lane = g & 63, nt = g >> 6;
    int n  = nt * 16 + (lane & 15);
    int k0 = (lane >> 4) * 8;
    bf16x8 v;
#pragma unroll
    for (int j = 0; j < 8; ++j) {
        int k = k0 + j;
        float f = 0.f;
        if (k < ND) f = (n < HID) ? wl[k * HID + n] : wr[k * HID + (n - HID)];
        v[j] = (bf16)f;
    }
    *(bf16x8*)(bp + ((size_t)nt * 64 + lane) * 8) = v;
}

// ============ K0d: pack g2 -> B-fragments ============
__global__ __launch_bounds__(256) void k_pack_g2(const float* __restrict__ wl,
                                                 const float* __restrict__ wr,
                                                 bf16* __restrict__ bp) {
    int g = blockIdx.x * 256 + threadIdx.x;
    int lane = g & 63, frag = g >> 6;
    int nt = frag >> 3, kt = frag & 7;
    int n  = nt * 16 + (lane & 15);
    int k0 = kt * 32 + (lane >> 4) * 8;
    bf16x8 v;
#pragma unroll
    for (int j = 0; j < 8; ++j) {
        int k = k0 + j;
        float f = (n < HID) ? wl[k * HID + n] : wr[k * HID + (n - HID)];
        v[j] = (bf16)f;
    }
    *(bf16x8*)(bp + ((size_t)frag * 64 + lane) * 8) = v;
}

// ============ K0e: build in/out CSR (parallel, deterministic) ============
__global__ __launch_bounds__(128) void k_csr_par(const int* __restrict__ ei,
                                                 int* __restrict__ csr) {
    __shared__ int es[NE], ed[NE], cnt[NN], ocnt[NN], off[NN + 1], ooff[NN + 1];
    int tid = threadIdx.x;
    if (tid < NN) { cnt[tid] = 0; ocnt[tid] = 0; }
    for (int e = tid; e < NE; e += 128) { es[e] = ei[e]; ed[e] = ei[NE + e]; }
    __syncthreads();
    for (int e = tid; e < NE; e += 128) {
        atomicAdd(&cnt[ed[e]], 1);
        atomicAdd(&ocnt[es[e]], 1);
    }
    __syncthreads();
    if (tid == 0) {
        off[0] = 0; ooff[0] = 0;
        for (int n = 0; n < NN; ++n) {
            off[n + 1] = off[n] + cnt[n];
            ooff[n + 1] = ooff[n] + ocnt[n];
        }
    }
    __syncthreads();
    if (tid < NN) {
        int p = off[tid];
        for (int e = 0; e < NE; ++e)
            if (ed[e] == tid) { csr[50 + p] = e; csr[411 + p] = es[e]; ++p; }
    } else if (tid >= 64 && tid < 64 + NN) {
        int n = tid - 64;
        int p = ooff[n];
        for (int e = 0; e < NE; ++e)
            if (es[e] == n) { csr[822 + p] = e; ++p; }
    }
    if (tid < 50) { csr[tid] = off[tid]; csr[772 + tid] = ooff[tid]; }
}

// ==== K1: transform GEMM -> node32 [B*49][32] bf16 (4 Mt/wave) ====
__global__ __launch_bounds__(256, 2) void k_gemm_node(const bf16* __restrict__ xp,
                                                      const bf16* __restrict__ wp,
                                                      const float* __restrict__ tb,
                                                      bf16* __restrict__ node32) {
    __shared__ bf16 L[128][148];
    __shared__ float tbS[144];
    int tid = threadIdx.x, lane = tid & 63, w = tid >> 6;
    int nb = blockIdx.y, C0 = nb * 130;
    int mt0 = blockIdx.x * 16 + w * 4;
    if (tid < 144) { int col = C0 + tid; tbS[tid] = (col < NOUT) ? tb[col] : 0.f; }
    f32x4 acc[4][9] = {};
    const bf16* wpB = wp + (size_t)(nb * NTB) * KT_X * 512;
    for (int kt = 0; kt < KT_X; ++kt) {
        bf16x8 a[4];
#pragma unroll
        for (int i = 0; i < 4; ++i)
            a[i] = *(const bf16x8*)(xp + (((size_t)(mt0 + i) * KT_X + kt) * 64 + lane) * 8);
#pragma unroll
        for (int j = 0; j < NTB; ++j) {
            bf16x8 b = *(const bf16x8*)(wpB + ((size_t)(j * KT_X + kt) * 64 + lane) * 8);
#pragma unroll
            for (int i = 0; i < 4; ++i)
                acc[i][j] = __builtin_amdgcn_mfma_f32_16x16x32_bf16(a[i], b, acc[i][j], 0, 0, 0);
        }
    }
    int c0 = lane & 15, r0 = (lane >> 4) * 4;
    int nodes = (nb == 9) ? 4 : 5;
    int total = 128 * nodes * 4;
    for (int half = 0; half < 2; ++half) {
        __syncthreads();
        if ((w >> 1) == half) {
            int lrbase = (w & 1) * 64;
#pragma unroll
            for (int i = 0; i < 4; ++i) {
#pragma unroll
                for (int j = 0; j < NTB; ++j) {
                    int col = j * 16 + c0;
                    float bias = tbS[col];
#pragma unroll
                    for (int r = 0; r < 4; ++r)
                        L[lrbase + i * 16 + r0 + r][col] = (bf16)(acc[i][j][r] + bias);
                }
            }
        }
        __syncthreads();
        int B0 = blockIdx.x * 256 + half * 128;
        for (int t = tid; t < total; t += 256) {
            int q = t & 3, t2 = t >> 2;
            int n_l = t2 % nodes, brow = t2 / nodes;
            bf16x8 o;
#pragma unroll
            for (int jj = 0; jj < 8; ++jj) {
                int d = q * 8 + jj;
                o[jj] = (d < ND) ? L[brow][n_l * 26 + d] : (bf16)0.f;
            }
            *(bf16x8*)(node32 + (((size_t)(B0 + brow) * NN + nb * 5 + n_l) * 32 + q * 8)) = o;
        }
    }
}

// ============ K1b: pooled node features (sum over 49 nodes) ============
__global__ __launch_bounds__(256) void k_pool(const bf16* __restrict__ node32,
                                              float* __restrict__ pN) {
    int b = blockIdx.x * 8 + (threadIdx.x >> 5);
    int d = threadIdx.x & 31;
    if (d >= ND) return;
    const bf16* base = node32 + (size_t)b * NN * 32 + d;
    float s = 0.f;
    for (int n = 0; n < NN; ++n) s += (float)base[n * 32];
    pN[b * ND + d] = s;
}

// ======= K_A: fused layer-1 GEMM (swapped-mfma epilogue) + edge phase 1 ====
// h1f layout: per-graph padded tiles: (((g*4 + mt)*8 + kt)*64 + (n&15) + 16*kg)*8
__global__ __launch_bounds__(512, 2) void k_fuse1(const bf16* __restrict__ n32,
                                                  const bf16* __restrict__ B1p,
                                                  bf16* __restrict__ h1f,
                                                  const float* __restrict__ att1,
                                                  const float* __restrict__ g1b,
                                                  const int* __restrict__ ei,
                                                  const int* __restrict__ csr) {
    __shared__ __align__(16) char X[NN * 1024];
    __shared__ __align__(16) float attS[256];
    __shared__ float sc[NE * 4], srden[NN * 4], bS[256];
    __shared__ int ieOff[50], ieId[NE], ieSrc[NE], srcS[NE], dstS[NE];

    int tid = threadIdx.x, lane = tid & 63, w = tid >> 6, g = blockIdx.x;

    for (int i = tid; i < 256; i += 512) { attS[i] = att1[i]; bS[i] = g1b[i]; }
    for (int i = tid; i < NE; i += 512) {
        srcS[i] = ei[i]; dstS[i] = ei[NE + i];
        ieId[i] = csr[50 + i]; ieSrc[i] = csr[411 + i];
    }
    if (tid < 50) ieOff[tid] = csr[tid];

    // ---- layer-1 GEMM: mfma(Wfrag as A, nodefrag as B) -> X swizzled ----
    {
        int mt = w & 3, ng = w >> 2;
        int m = mt * 16 + (lane & 15);
        bf16x8 bfrag = {};
        if (m < NN)
            bfrag = *(const bf16x8*)(n32 + ((size_t)(g * NN + m) * 32 + (lane >> 4) * 8));
        int chq = (lane >> 4) * 4;
        int sw = (m & 7) << 4;
        char* rowp = X + m * 1024;
#pragma unroll
        for (int j = 0; j < 16; ++j) {
            f32x4 z = {0.f, 0.f, 0.f, 0.f};
            bf16x8 afrag = *(const bf16x8*)(B1p + ((size_t)(ng * 16 + j) * 64 + lane) * 8);
            f32x4 acc = __builtin_amdgcn_mfma_f32_16x16x32_bf16(afrag, bfrag, z, 0, 0, 0);
            if (m < NN) {
                int ch = (ng * 16 + j) * 16 + chq;
                bf16x4 o4;
#pragma unroll
                for (int r = 0; r < 4; ++r) o4[r] = (bf16)acc[r];
                *(bf16x4*)(rowp + ((ch * 2) ^ sw)) = o4;
            }
        }
    }
    __syncthreads();

    int rot = tid & 7;
    for (int task = tid; task < NE * 4; task += 512) {
        int h = task / NE, e = task - h * NE;
        int s = srcS[e], d = dstS[e];
        int sws = (s & 7) << 4, swd = (d & 7) << 4;
        const char* ps = X + s * 1024;
        const char* pd = X + d * 1024;
        float pa[4] = {0.f, 0.f, 0.f, 0.f};
#pragma unroll
        for (int i = 0; i < 8; ++i) {
            int cc = ((i + rot) & 7) * 8;
            bf16x8 xl = *(const bf16x8*)(ps + (((h * 64 + cc) * 2) ^ sws));
            bf16x8 xr = *(const bf16x8*)(pd + (((256 + h * 64 + cc) * 2) ^ swd));
            float4 a0 = *(const float4*)(attS + h * 64 + cc);
            float4 a1 = *(const float4*)(attS + h * 64 + cc + 4);
            const float aa[8] = {a0.x, a0.y, a0.z, a0.w, a1.x, a1.y, a1.z, a1.w};
#pragma unroll
            for (int q = 0; q < 8; ++q) {
                float v = (float)xl[q] + (float)xr[q];
                v = v > 0.f ? v : 0.2f * v;
                pa[q & 3] = fmaf(aa[q], v, pa[q & 3]);
            }
        }
        sc[e * 4 + h] = (pa[0] + pa[1]) + (pa[2] + pa[3]);
    }
    __syncthreads();
    for (int t = tid; t < NN * 4; t += 512) {
        int n = t >> 2, h = t & 3;
        float m = -1e30f;
        for (int j = ieOff[n]; j < ieOff[n + 1]; ++j) m = fmaxf(m, sc[ieId[j] * 4 + h]);
        float den = 0.f;
        for (int j = ieOff[n]; j < ieOff[n + 1]; ++j) {
            int idx = ieId[j] * 4 + h;
            float ex = __expf(sc[idx] - m);
            sc[idx] = ex; den += ex;
        }
        srden[t] = 1.f / den;
    }
    __syncthreads();
    for (int task = tid; task < NN * 32; task += 512) {
        int n = task >> 5, cb = task & 31;
        int ch0 = cb * 8, hh = cb >> 3;
        float a8[8] = {};
        int j0 = ieOff[n], j1 = ieOff[n + 1];
        for (int j = j0; j < j1; ++j) {
            float al = sc[ieId[j] * 4 + hh];
            int s = ieSrc[j];
            bf16x8 xv = *(const bf16x8*)(X + s * 1024 + ((ch0 * 2) ^ ((s & 7) << 4)));
#pragma unroll
            for (int q = 0; q < 8; ++q) a8[q] = fmaf(al, (float)xv[q], a8[q]);
        }
        float rs = srden[n * 4 + hh];
        bf16x8 o;
#pragma unroll
        for (int q = 0; q < 8; ++q) {
            float v = fmaf(a8[q], rs, bS[ch0 + q]);
            v = v > 0.f ? v : (__expf(v) - 1.f);
            o[q] = (bf16)v;
        }
        int kt = ch0 >> 5, kg = (ch0 >> 3) & 3;
        size_t addr = ((((size_t)g * 4 + (n >> 4)) * 8 + kt) * 64 + (n & 15) + 16 * kg) * 8;
        *(bf16x8*)(h1f + addr) = o;
    }
}

// == K_B: per-graph layer-2 GEMM (into LDS) + scores + softmax + pool + FC ==
static __device__ __forceinline__ float waveReduceSum(float v) {
#pragma unroll
    for (int m = 32; m > 0; m >>= 1) v += __shfl_xor(v, m, 64);
    return v;
}

__global__ __launch_bounds__(256, 2) void k_fuse2(const bf16* __restrict__ h1f,
                                                  const bf16* __restrict__ B2p,
                                                  const float* __restrict__ att2,
                                                  const float* __restrict__ pN,
                                                  const float* __restrict__ g2b,
                                                  const float* __restrict__ fcw,
                                                  const float* __restrict__ fcb,
                                                  const int* __restrict__ ei,
                                                  const int* __restrict__ csr,
                                                  int graph_base,
                                                  float* __restrict__ out) {
    __shared__ __align__(16) char X[NN * 1024];
    __shared__ float attS[256];
    __shared__ float sc[NE], sm[NN], sr[NN], wS[NN];
    __shared__ float poolS[288];
    int tid = threadIdx.x, lane = tid & 63, w = tid >> 6, g = blockIdx.x;

    if (tid < 256) attS[tid] = att2[tid];
    if (tid < ND) poolS[tid] = pN[(size_t)(graph_base + g) * ND + tid] * (1.f / NN);

    // ---- layer-2 GEMM: mfma(B2frag as A, h1frag as B) -> X swizzled ----
    // wave w: mt pair = (w&1)*2+{0,1}; col half = w>>1 (nt = half*16 + j)
    {
        int mtp = w & 1, chf = w >> 1;
        f32x4 acc0[16] = {};
        f32x4 acc1[16] = {};
        const bf16* aBase0 = h1f + (((size_t)g * 4 + mtp * 2 + 0) * 8) * 512;
        const bf16* aBase1 = h1f + (((size_t)g * 4 + mtp * 2 + 1) * 8) * 512;
        for (int kt = 0; kt < 8; ++kt) {
            bf16x8 a0 = *(const bf16x8*)(aBase0 + ((size_t)kt * 64 + lane) * 8);
            bf16x8 a1 = *(const bf16x8*)(aBase1 + ((size_t)kt * 64 + lane) * 8);
#pragma unroll
            for (int j = 0; j < 16; ++j) {
                int nt = chf * 16 + j;
                bf16x8 b = *(const bf16x8*)(B2p + (((size_t)nt * 8 + kt) * 64 + lane) * 8);
                acc0[j] = __builtin_amdgcn_mfma_f32_16x16x32_bf16(b, a0, acc0[j], 0, 0, 0);
                acc1[j] = __builtin_amdgcn_mfma_f32_16x16x32_bf16(b, a1, acc1[j], 0, 0, 0);
            }
        }
        // epilogue: lane holds node = mt*16 + (lane&15), 4 channels
        int chq = (lane >> 4) * 4;
#pragma unroll
        for (int i = 0; i < 2; ++i) {
            int n = (mtp * 2 + i) * 16 + (lane & 15);
            if (n < NN) {
                int sw = (n & 7) << 4;
                char* rowp = X + n * 1024;
#pragma unroll
                for (int j = 0; j < 16; ++j) {
                    int ch = (chf * 16 + j) * 16 + chq;
                    f32x4 acc = i ? acc1[j] : acc0[j];
                    bf16x4 o4;
#pragma unroll
                    for (int r = 0; r < 4; ++r) o4[r] = (bf16)acc[r];
                    *(bf16x4*)(rowp + ((ch * 2) ^ sw)) = o4;
                }
            }
        }
    }
    __syncthreads();

    // ---- scores (thread per edge, 2 passes) ----
    for (int e = tid; e < NE; e += 256) {
        int s = ei[e], d = ei[NE + e];
        int sws = (s & 7) << 4, swd = (d & 7) << 4;
        const char* ps = X + s * 1024;
        const char* pd = X + d * 1024;
        int rot = e & 7;
        float pa[4] = {0.f, 0.f, 0.f, 0.f};
#pragma unroll 8
        for (int i = 0; i < 32; ++i) {
            int cc = ((i + rot) & 31) * 8;
            bf16x8 xl = *(const bf16x8*)(ps + ((cc * 2) ^ sws));
            bf16x8 xr = *(const bf16x8*)(pd + (((256 + cc) * 2) ^ swd));
            float4 a0 = *(const float4*)(attS + cc);
            float4 a1 = *(const float4*)(attS + cc + 4);
            const float aa[8] = {a0.x, a0.y, a0.z, a0.w, a1.x, a1.y, a1.z, a1.w};
#pragma unroll
            for (int q = 0; q < 8; ++q) {
                float v = (float)xl[q] + (float)xr[q];
                v = v > 0.f ? v : 0.2f * v;
                pa[q & 3] = fmaf(aa[q], v, pa[q & 3]);
            }
        }
        sc[e] = (pa[0] + pa[1]) + (pa[2] + pa[3]);
    }
    __syncthreads();
    // ---- softmax stats ----
    if (tid < NN) {
        int j0 = csr[tid], j1 = csr[tid + 1];
        float m = -1e30f;
        for (int j = j0; j < j1; ++j) m = fmaxf(m, sc[csr[50 + j]]);
        float den = 0.f;
        for (int j = j0; j < j1; ++j) den += __expf(sc[csr[50 + j]] - m);
        sm[tid] = m; sr[tid] = 1.f / den;
    }
    __syncthreads();
    // ---- out-node alpha sums ----
    if (tid < NN) {
        float wa = 0.f;
        int j0 = csr[772 + tid], j1 = csr[772 + tid + 1];
        for (int j = j0; j < j1; ++j) {
            int e = csr[822 + j];
            int d = ei[NE + e];
            wa += __expf(sc[e] - sm[d]) * sr[d];
        }
        wS[tid] = wa;
    }
    __syncthreads();
    // ---- pooled g from LDS (thread per channel) ----
    {
        float acc = 0.f;
#pragma unroll
        for (int n = 0; n < NN; ++n) {
            float v = (float)*(const bf16*)(X + n * 1024 + ((tid * 2) ^ ((n & 7) << 4)));
            acc = fmaf(wS[n], v, acc);
        }
        poolS[ND + tid] = acc * (1.f / NN) + g2b[tid];
    }
    __syncthreads();
    // ---- FC (4 waves cover 5 outputs) ----
    for (int o = w; o < 5; o += 4) {
        float a = 0.f;
        for (int d = lane; d < ND + HID; d += 64) a = fmaf(poolS[d], fcw[d * 5 + o], a);
        a = waveReduceSum(a);
        if (lane == 0) out[(size_t)(graph_base + g) * 5 + o] = a + fcb[o];
    }
}

// ============ launch ============
extern "C" void kernel_launch(void* const* d_in, const int* in_sizes, int n_in,
                              void* d_out, int out_size, void* d_ws, size_t ws_size,
                              hipStream_t stream) {
    const float* x   = (const float*)d_in[0];
    const float* tw  = (const float*)d_in[1];
    const float* tb  = (const float*)d_in[2];
    const float* wl1 = (const float*)d_in[3];
    const float* wr1 = (const float*)d_in[4];
    const float* at1 = (const float*)d_in[5];
    const float* b1  = (const float*)d_in[6];
    const float* wl2 = (const float*)d_in[7];
    const float* wr2 = (const float*)d_in[8];
    const float* at2 = (const float*)d_in[9];
    const float* b2  = (const float*)d_in[10];
    const float* fcw = (const float*)d_in[11];
    const float* fcb = (const float*)d_in[12];
    const int*   ei  = (const int*)d_in[13];
    float* out = (float*)d_out;

    char* ws = (char*)d_ws;
    bf16*  xp   = (bf16*)(ws + OFF_XPACK);
    bf16*  wp   = (bf16*)(ws + OFF_WPACK);
    bf16*  b1p  = (bf16*)(ws + OFF_B1);
    bf16*  b2p  = (bf16*)(ws + OFF_B2);
    bf16*  n32  = (bf16*)(ws + OFF_N32);
    float* pN   = (float*)(ws + OFF_PN);
    int*   csr  = (int*)(ws + OFF_CSR);

    // chunk buffer: h1f = C * 4mt*8kt*64*8*2 = C*32768 bytes
    const size_t perC = 32768;
    int C = 512;
    for (int cand : {2048, 1024, 512}) {
        if (OFF_CHUNK + (size_t)cand * perC <= ws_size) { C = cand; break; }
    }
    bf16* h1f = (bf16*)(ws + OFF_CHUNK);
    int nchunks = BATCH / C;

    k_pack_x<<<dim3(MT_X * KT_X * 64 / 256), dim3(256), 0, stream>>>(x, xp);
    k_pack_w<<<dim3(NB_W * NTB * KT_X * 64 / 256), dim3(256), 0, stream>>>(tw, wp);
    k_pack_g1<<<dim3(8), dim3(256), 0, stream>>>(wl1, wr1, b1p);
    k_pack_g2<<<dim3(64), dim3(256), 0, stream>>>(wl2, wr2, b2p);
    k_csr_par<<<dim3(1), dim3(128), 0, stream>>>(ei, csr);
    k_gemm_node<<<dim3(32, NB_W), dim3(256), 0, stream>>>(xp, wp, tb, n32);
    k_pool<<<dim3(BATCH / 8), dim3(256), 0, stream>>>(n32, pN);

    for (int c = 0; c < nchunks; ++c) {
        const bf16* n32c = n32 + (size_t)c * C * NN * 32;
        k_fuse1<<<dim3(C), dim3(512), 0, stream>>>(n32c, b1p, h1f, at1, b1, ei, csr);
        k_fuse2<<<dim3(C), dim3(256), 0, stream>>>(h1f, b2p, at2, pN, b2, fcw, fcb,
                                                   ei, csr, c * C, out);
    }
}

// Round 13
// 939.291 us; speedup vs baseline: 1.3442x; 1.0248x over previous
//
#include <hip/hip_runtime.h>
#include <hip/hip_bf16.h>

typedef __bf16 bf16;
typedef __attribute__((ext_vector_type(8))) __bf16 bf16x8;
typedef __attribute__((ext_vector_type(4))) __bf16 bf16x4;
typedef __attribute__((ext_vector_type(4))) float f32x4;

constexpr int BATCH = 8192, NN = 49, ND = 26, NOUT = 1274, FD = 1280;
constexpr int HID = 256, NE = 361, HEADS = 4;
constexpr int KT_X = 40;
constexpr int MT_X = 512;
constexpr int NB_W = 10;
constexpr int NTB  = 9;

// ---- workspace layout (bytes) ----
constexpr size_t OFF_XPACK = 0;
constexpr size_t SZ_XPACK  = (size_t)MT_X * KT_X * 512 * 2;
constexpr size_t OFF_WPACK = OFF_XPACK + SZ_XPACK;
constexpr size_t SZ_WPACK  = (size_t)NB_W * NTB * KT_X * 512 * 2;
constexpr size_t OFF_B1    = OFF_WPACK + SZ_WPACK;
constexpr size_t SZ_B1     = (size_t)32 * 512 * 2;
constexpr size_t OFF_B2    = OFF_B1 + SZ_B1;
constexpr size_t SZ_B2     = (size_t)32 * 8 * 512 * 2;
constexpr size_t OFF_N32   = OFF_B2 + SZ_B2;
constexpr size_t SZ_N32    = (size_t)BATCH * NN * 32 * 2;
constexpr size_t OFF_PN    = OFF_N32 + SZ_N32;
constexpr size_t SZ_PN     = (size_t)BATCH * ND * 4;
constexpr size_t OFF_CSR   = OFF_PN + SZ_PN;
constexpr size_t SZ_CSR    = 8192;
constexpr size_t OFF_CHUNK = OFF_CSR + SZ_CSR;

// csr int layout: [0..49] in-off | [50..410] in-edge id | [411..771] in-edge src
//                 [772..821] out-off | [822..1182] out-edge id

// ============ K0a: pack x -> A-fragments bf16 ============
__global__ __launch_bounds__(256) void k_pack_x(const float* __restrict__ x,
                                                bf16* __restrict__ xp) {
    int g = blockIdx.x * 256 + threadIdx.x;
    int lane = g & 63, frag = g >> 6;
    int mt = frag / KT_X, kt = frag - mt * KT_X;
    int row = mt * 16 + (lane & 15);
    int k0  = kt * 32 + (lane >> 4) * 8;
    const float* src = x + (size_t)row * FD + k0;
    bf16x8 v;
#pragma unroll
    for (int j = 0; j < 8; ++j) v[j] = (bf16)src[j];
    *(bf16x8*)(xp + ((size_t)frag * 64 + lane) * 8) = v;
}

// ======== K0b: pack transform_w -> B-frags, node-aligned col-blocks ========
__global__ __launch_bounds__(256) void k_pack_w(const float* __restrict__ w,
                                                bf16* __restrict__ wp) {
    int g = blockIdx.x * 256 + threadIdx.x;
    int lane = g & 63, frag = g >> 6;
    int kt = frag % KT_X, t2 = frag / KT_X;
    int nt = t2 % NTB, nb = t2 / NTB;
    int col = nb * 130 + nt * 16 + (lane & 15);
    int k0  = kt * 32 + (lane >> 4) * 8;
    bool ok = (col < NOUT) && (col < nb * 130 + 130);
    bf16x8 v;
#pragma unroll
    for (int j = 0; j < 8; ++j)
        v[j] = ok ? (bf16)w[(size_t)(k0 + j) * NOUT + col] : (bf16)0.f;
    *(bf16x8*)(wp + ((size_t)frag * 64 + lane) * 8) = v;
}

// ============ K0c: pack g1 -> B-fragments ============
__global__ __launch_bounds__(256) void k_pack_g1(const float* __restrict__ wl,
                                                 const float* __restrict__ wr,
                                                 bf16* __restrict__ bp) {
    int g = blockIdx.x * 256 + threadIdx.x;
    int lane = g & 63, nt = g >> 6;
    int n  = nt * 16 + (lane & 15);
    int k0 = (lane >> 4) * 8;
    bf16x8 v;
#pragma unroll
    for (int j = 0; j < 8; ++j) {
        int k = k0 + j;
        float f = 0.f;
        if (k < ND) f = (n < HID) ? wl[k * HID + n] : wr[k * HID + (n - HID)];
        v[j] = (bf16)f;
    }
    *(bf16x8*)(bp + ((size_t)nt * 64 + lane) * 8) = v;
}

// ============ K0d: pack g2 -> B-fragments ============
__global__ __launch_bounds__(256) void k_pack_g2(const float* __restrict__ wl,
                                                 const float* __restrict__ wr,
                                                 bf16* __restrict__ bp) {
    int g = blockIdx.x * 256 + threadIdx.x;
    int lane = g & 63, frag = g >> 6;
    int nt = frag >> 3, kt = frag & 7;
    int n  = nt * 16 + (lane & 15);
    int k0 = kt * 32 + (lane >> 4) * 8;
    bf16x8 v;
#pragma unroll
    for (int j = 0; j < 8; ++j) {
        int k = k0 + j;
        float f = (n < HID) ? wl[k * HID + n] : wr[k * HID + (n - HID)];
        v[j] = (bf16)f;
    }
    *(bf16x8*)(bp + ((size_t)frag * 64 + lane) * 8) = v;
}

// ============ K0e: build in/out CSR (parallel, deterministic) ============
__global__ __launch_bounds__(128) void k_csr_par(const int* __restrict__ ei,
                                                 int* __restrict__ csr) {
    __shared__ int es[NE], ed[NE], cnt[NN], ocnt[NN], off[NN + 1], ooff[NN + 1];
    int tid = threadIdx.x;
    if (tid < NN) { cnt[tid] = 0; ocnt[tid] = 0; }
    for (int e = tid; e < NE; e += 128) { es[e] = ei[e]; ed[e] = ei[NE + e]; }
    __syncthreads();
    for (int e = tid; e < NE; e += 128) {
        atomicAdd(&cnt[ed[e]], 1);
        atomicAdd(&ocnt[es[e]], 1);
    }
    __syncthreads();
    if (tid == 0) {
        off[0] = 0; ooff[0] = 0;
        for (int n = 0; n < NN; ++n) {
            off[n + 1] = off[n] + cnt[n];
            ooff[n + 1] = ooff[n] + ocnt[n];
        }
    }
    __syncthreads();
    if (tid < NN) {
        int p = off[tid];
        for (int e = 0; e < NE; ++e)
            if (ed[e] == tid) { csr[50 + p] = e; csr[411 + p] = es[e]; ++p; }
    } else if (tid >= 64 && tid < 64 + NN) {
        int n = tid - 64;
        int p = ooff[n];
        for (int e = 0; e < NE; ++e)
            if (es[e] == n) { csr[822 + p] = e; ++p; }
    }
    if (tid < 50) { csr[tid] = off[tid]; csr[772 + tid] = ooff[tid]; }
}

// ==== K1: transform GEMM -> node32 [B*49][32] bf16 (4 Mt/wave) ====
__global__ __launch_bounds__(256, 2) void k_gemm_node(const bf16* __restrict__ xp,
                                                      const bf16* __restrict__ wp,
                                                      const float* __restrict__ tb,
                                                      bf16* __restrict__ node32) {
    __shared__ bf16 L[128][148];
    __shared__ float tbS[144];
    int tid = threadIdx.x, lane = tid & 63, w = tid >> 6;
    int nb = blockIdx.y, C0 = nb * 130;
    int mt0 = blockIdx.x * 16 + w * 4;
    if (tid < 144) { int col = C0 + tid; tbS[tid] = (col < NOUT) ? tb[col] : 0.f; }
    f32x4 acc[4][9] = {};
    const bf16* wpB = wp + (size_t)(nb * NTB) * KT_X * 512;
    for (int kt = 0; kt < KT_X; ++kt) {
        bf16x8 a[4];
#pragma unroll
        for (int i = 0; i < 4; ++i)
            a[i] = *(const bf16x8*)(xp + (((size_t)(mt0 + i) * KT_X + kt) * 64 + lane) * 8);
#pragma unroll
        for (int j = 0; j < NTB; ++j) {
            bf16x8 b = *(const bf16x8*)(wpB + ((size_t)(j * KT_X + kt) * 64 + lane) * 8);
#pragma unroll
            for (int i = 0; i < 4; ++i)
                acc[i][j] = __builtin_amdgcn_mfma_f32_16x16x32_bf16(a[i], b, acc[i][j], 0, 0, 0);
        }
    }
    int c0 = lane & 15, r0 = (lane >> 4) * 4;
    int nodes = (nb == 9) ? 4 : 5;
    int total = 128 * nodes * 4;
    for (int half = 0; half < 2; ++half) {
        __syncthreads();
        if ((w >> 1) == half) {
            int lrbase = (w & 1) * 64;
#pragma unroll
            for (int i = 0; i < 4; ++i) {
#pragma unroll
                for (int j = 0; j < NTB; ++j) {
                    int col = j * 16 + c0;
                    float bias = tbS[col];
#pragma unroll
                    for (int r = 0; r < 4; ++r)
                        L[lrbase + i * 16 + r0 + r][col] = (bf16)(acc[i][j][r] + bias);
                }
            }
        }
        __syncthreads();
        int B0 = blockIdx.x * 256 + half * 128;
        for (int t = tid; t < total; t += 256) {
            int q = t & 3, t2 = t >> 2;
            int n_l = t2 % nodes, brow = t2 / nodes;
            bf16x8 o;
#pragma unroll
            for (int jj = 0; jj < 8; ++jj) {
                int d = q * 8 + jj;
                o[jj] = (d < ND) ? L[brow][n_l * 26 + d] : (bf16)0.f;
            }
            *(bf16x8*)(node32 + (((size_t)(B0 + brow) * NN + nb * 5 + n_l) * 32 + q * 8)) = o;
        }
    }
}

// ============ K1b: pooled node features (sum over 49 nodes) ============
__global__ __launch_bounds__(256) void k_pool(const bf16* __restrict__ node32,
                                              float* __restrict__ pN) {
    int b = blockIdx.x * 8 + (threadIdx.x >> 5);
    int d = threadIdx.x & 31;
    if (d >= ND) return;
    const bf16* base = node32 + (size_t)b * NN * 32 + d;
    float s = 0.f;
    for (int n = 0; n < NN; ++n) s += (float)base[n * 32];
    pN[b * ND + d] = s;
}

// ======= K_A: fused layer-1 GEMM (swapped-mfma epilogue) + edge phase 1 ====
__global__ __launch_bounds__(512, 2) void k_fuse1(const bf16* __restrict__ n32,
                                                  const bf16* __restrict__ B1p,
                                                  bf16* __restrict__ h1f,
                                                  const float* __restrict__ att1,
                                                  const float* __restrict__ g1b,
                                                  const int* __restrict__ ei,
                                                  const int* __restrict__ csr) {
    __shared__ __align__(16) char X[NN * 1024];
    __shared__ __align__(16) float attS[256];
    __shared__ float sc[NE * 4], srden[NN * 4], bS[256];
    __shared__ int ieOff[50], ieId[NE], ieSrc[NE], srcS[NE], dstS[NE];

    int tid = threadIdx.x, lane = tid & 63, w = tid >> 6, g = blockIdx.x;

    for (int i = tid; i < 256; i += 512) { attS[i] = att1[i]; bS[i] = g1b[i]; }
    for (int i = tid; i < NE; i += 512) {
        srcS[i] = ei[i]; dstS[i] = ei[NE + i];
        ieId[i] = csr[50 + i]; ieSrc[i] = csr[411 + i];
    }
    if (tid < 50) ieOff[tid] = csr[tid];

    // ---- layer-1 GEMM: mfma(Wfrag as A, nodefrag as B) -> X swizzled ----
    {
        int mt = w & 3, ng = w >> 2;
        int m = mt * 16 + (lane & 15);
        bf16x8 bfrag = {};
        if (m < NN)
            bfrag = *(const bf16x8*)(n32 + ((size_t)(g * NN + m) * 32 + (lane >> 4) * 8));
        int chq = (lane >> 4) * 4;
        int sw = (m & 7) << 4;
        char* rowp = X + m * 1024;
#pragma unroll
        for (int j = 0; j < 16; ++j) {
            f32x4 z = {0.f, 0.f, 0.f, 0.f};
            bf16x8 afrag = *(const bf16x8*)(B1p + ((size_t)(ng * 16 + j) * 64 + lane) * 8);
            f32x4 acc = __builtin_amdgcn_mfma_f32_16x16x32_bf16(afrag, bfrag, z, 0, 0, 0);
            if (m < NN) {
                int ch = (ng * 16 + j) * 16 + chq;
                bf16x4 o4;
#pragma unroll
                for (int r = 0; r < 4; ++r) o4[r] = (bf16)acc[r];
                *(bf16x4*)(rowp + ((ch * 2) ^ sw)) = o4;
            }
        }
    }
    __syncthreads();

    // ---- scores: bank-uniform slot order (stored xl slot = (i+lane)&7) ----
    int lrot = tid & 7;
    for (int task = tid; task < NE * 4; task += 512) {
        int h = task / NE, e = task - h * NE;
        int s = srcS[e], d = dstS[e];
        int s7 = s & 7;
        int sws = s7 << 4, swd = (d & 7) << 4;
        const char* ps = X + s * 1024;
        const char* pd = X + d * 1024;
        float pa[4] = {0.f, 0.f, 0.f, 0.f};
#pragma unroll
        for (int i = 0; i < 8; ++i) {
            int cc = (((i + lrot) & 7) ^ s7) * 8;     // logical block; stored slot uniform
            bf16x8 xl = *(const bf16x8*)(ps + (((h * 64 + cc) * 2) ^ sws));
            bf16x8 xr = *(const bf16x8*)(pd + (((256 + h * 64 + cc) * 2) ^ swd));
            float4 a0 = *(const float4*)(attS + h * 64 + cc);
            float4 a1 = *(const float4*)(attS + h * 64 + cc + 4);
            const float aa[8] = {a0.x, a0.y, a0.z, a0.w, a1.x, a1.y, a1.z, a1.w};
#pragma unroll
            for (int q = 0; q < 8; ++q) {
                float v = (float)xl[q] + (float)xr[q];
                v = v > 0.f ? v : 0.2f * v;
                pa[q & 3] = fmaf(aa[q], v, pa[q & 3]);
            }
        }
        sc[e * 4 + h] = (pa[0] + pa[1]) + (pa[2] + pa[3]);
    }
    __syncthreads();
    for (int t = tid; t < NN * 4; t += 512) {
        int n = t >> 2, h = t & 3;
        float m = -1e30f;
        for (int j = ieOff[n]; j < ieOff[n + 1]; ++j) m = fmaxf(m, sc[ieId[j] * 4 + h]);
        float den = 0.f;
        for (int j = ieOff[n]; j < ieOff[n + 1]; ++j) {
            int idx = ieId[j] * 4 + h;
            float ex = __expf(sc[idx] - m);
            sc[idx] = ex; den += ex;
        }
        srden[t] = 1.f / den;
    }
    __syncthreads();
    for (int task = tid; task < NN * 32; task += 512) {
        int n = task >> 5, cb = task & 31;
        int ch0 = cb * 8, hh = cb >> 3;
        float a8[8] = {};
        int j0 = ieOff[n], j1 = ieOff[n + 1];
        for (int j = j0; j < j1; ++j) {
            float al = sc[ieId[j] * 4 + hh];
            int s = ieSrc[j];
            bf16x8 xv = *(const bf16x8*)(X + s * 1024 + ((ch0 * 2) ^ ((s & 7) << 4)));
#pragma unroll
            for (int q = 0; q < 8; ++q) a8[q] = fmaf(al, (float)xv[q], a8[q]);
        }
        float rs = srden[n * 4 + hh];
        bf16x8 o;
#pragma unroll
        for (int q = 0; q < 8; ++q) {
            float v = fmaf(a8[q], rs, bS[ch0 + q]);
            v = v > 0.f ? v : (__expf(v) - 1.f);
            o[q] = (bf16)v;
        }
        int Rl = g * NN + n;
        int kt = ch0 >> 5, kg = (ch0 >> 3) & 3;
        size_t addr = (((size_t)(Rl >> 4) * 8 + kt) * 64 + (Rl & 15) + 16 * kg) * 8;
        *(bf16x8*)(h1f + addr) = o;
    }
}

// ==== K_B1: batched layer-2 GEMM (h1 frags -> LINEAR row-major xlr) ========
__global__ __launch_bounds__(256) void k_gemm_l2(const bf16* __restrict__ Af,
                                                 const bf16* __restrict__ Bf,
                                                 bf16* __restrict__ xlr) {
    __shared__ bf16 LT[128][136];
    int tid = threadIdx.x, lane = tid & 63, w = tid >> 6;
    int mtb = blockIdx.x * 8 + (w >> 1) * 4;
    int ntb = blockIdx.y * 8 + (w & 1) * 4;
    f32x4 acc[4][4] = {};
    for (int kt = 0; kt < 8; ++kt) {
        bf16x8 a[4], b[4];
#pragma unroll
        for (int i = 0; i < 4; ++i)
            a[i] = *(const bf16x8*)(Af + (((size_t)(mtb + i) * 8 + kt) * 64 + lane) * 8);
#pragma unroll
        for (int j = 0; j < 4; ++j)
            b[j] = *(const bf16x8*)(Bf + (((size_t)(ntb + j) * 8 + kt) * 64 + lane) * 8);
#pragma unroll
        for (int i = 0; i < 4; ++i)
#pragma unroll
            for (int j = 0; j < 4; ++j)
                acc[i][j] = __builtin_amdgcn_mfma_f32_16x16x32_bf16(a[i], b[j], acc[i][j], 0, 0, 0);
    }
    int c0 = lane & 15, r0 = (lane >> 4) * 4;
    int lr0 = (w >> 1) * 64, lc0 = (w & 1) * 64;
#pragma unroll
    for (int i = 0; i < 4; ++i)
#pragma unroll
        for (int j = 0; j < 4; ++j)
#pragma unroll
            for (int r = 0; r < 4; ++r)
                LT[lr0 + i * 16 + r0 + r][lc0 + j * 16 + c0] = (bf16)acc[i][j][r];
    __syncthreads();
    size_t R0 = (size_t)blockIdx.x * 128, C0 = (size_t)blockIdx.y * 128;
#pragma unroll
    for (int it = 0; it < 8; ++it) {
        int idx = (it * 256 + tid) * 8;
        int r = idx >> 7, c = idx & 127;
        bf16x8 v = *(const bf16x8*)&LT[r][c];
        *(bf16x8*)(xlr + (R0 + r) * 512 + C0 + c) = v;
    }
}

// ====== K_B2a: layer-2 edge scores, X staged ONCE in LDS (block/graph) =====
__global__ __launch_bounds__(384) void k_score2(const bf16* __restrict__ xlr,
                                                const float* __restrict__ att2,
                                                const int* __restrict__ ei,
                                                float* __restrict__ scE) {
    __shared__ __align__(16) char X[NN * 1024];
    __shared__ float attS[256];
    int tid = threadIdx.x, g = blockIdx.x;
    const char* srcp = (const char*)(xlr + (size_t)g * NN * 512);
    for (int off = tid * 16; off < NN * 1024; off += 384 * 16) {
        int row = off >> 10;
        *(uint4*)(X + (off ^ ((row & 7) << 4))) = *(const uint4*)(srcp + off);
    }
    if (tid < 256) attS[tid] = att2[tid];
    __syncthreads();
    if (tid >= NE) return;
    int s = ei[tid], d = ei[NE + tid];
    int s7 = s & 7;
    int sws = s7 << 4, swd = (d & 7) << 4;
    const char* ps = X + s * 1024;
    const char* pd = X + d * 1024;
    int rot = tid & 7;
    float pa[4] = {0.f, 0.f, 0.f, 0.f};
#pragma unroll 8
    for (int i = 0; i < 32; ++i) {
        int jb = (i + rot) & 31;
        int cc = ((jb & ~7) | ((jb & 7) ^ s7)) * 8;   // stored xl slot uniform
        bf16x8 xl = *(const bf16x8*)(ps + ((cc * 2) ^ sws));
        bf16x8 xr = *(const bf16x8*)(pd + (((256 + cc) * 2) ^ swd));
        float4 a0 = *(const float4*)(attS + cc);
        float4 a1 = *(const float4*)(attS + cc + 4);
        const float aa[8] = {a0.x, a0.y, a0.z, a0.w, a1.x, a1.y, a1.z, a1.w};
#pragma unroll
        for (int q = 0; q < 8; ++q) {
            float v = (float)xl[q] + (float)xr[q];
            v = v > 0.f ? v : 0.2f * v;
            pa[q & 3] = fmaf(aa[q], v, pa[q & 3]);
        }
    }
    scE[(size_t)g * NE + tid] = (pa[0] + pa[1]) + (pa[2] + pa[3]);
}

// ====== K_B2b: per-graph softmax stats + out-node weights (64 thr) =========
__global__ __launch_bounds__(64) void k_softwn(const float* __restrict__ scE,
                                               const int* __restrict__ csr,
                                               const int* __restrict__ ei,
                                               float* __restrict__ wN) {
    __shared__ float sm[NN], sr[NN];
    int g = blockIdx.x, tid = threadIdx.x;
    const float* sg = scE + (size_t)g * NE;
    if (tid < NN) {
        int j0 = csr[tid], j1 = csr[tid + 1];
        float m = -1e30f;
        for (int j = j0; j < j1; ++j) m = fmaxf(m, sg[csr[50 + j]]);
        float den = 0.f;
        for (int j = j0; j < j1; ++j) den += __expf(sg[csr[50 + j]] - m);
        sm[tid] = m; sr[tid] = 1.f / den;
    }
    __syncthreads();
    if (tid < NN) {
        float wa = 0.f;
        int j0 = csr[772 + tid], j1 = csr[772 + tid + 1];
        for (int j = j0; j < j1; ++j) {
            int e = csr[822 + j];
            int d = ei[NE + e];
            wa += __expf(sg[e] - sm[d]) * sr[d];
        }
        wN[(size_t)g * NN + tid] = wa;
    }
}

// ============ K_B2d: pooled g + FC (block per graph, lean LDS) ============
static __device__ __forceinline__ float waveReduceSum(float v) {
#pragma unroll
    for (int m = 32; m > 0; m >>= 1) v += __shfl_xor(v, m, 64);
    return v;
}

__global__ __launch_bounds__(256) void k_poolfc(const bf16* __restrict__ xlr,
                                                const float* __restrict__ wN,
                                                const float* __restrict__ pN,
                                                const float* __restrict__ g2b,
                                                const float* __restrict__ fcw,
                                                const float* __restrict__ fcb,
                                                int graph_base,
                                                float* __restrict__ out) {
    __shared__ float wSs[NN];
    __shared__ float poolS[288];
    int tid = threadIdx.x, g = blockIdx.x;
    if (tid < NN) wSs[tid] = wN[(size_t)g * NN + tid];
    if (tid >= 64 && tid < 64 + ND)
        poolS[tid - 64] = pN[(size_t)(graph_base + g) * ND + (tid - 64)] * (1.f / NN);
    __syncthreads();
    {
        const bf16* base = xlr + (size_t)g * NN * 512 + tid;
        float acc = 0.f;
        for (int n = 0; n < NN; ++n) acc = fmaf(wSs[n], (float)base[n * 512], acc);
        poolS[ND + tid] = acc * (1.f / NN) + g2b[tid];
    }
    __syncthreads();
    int w5 = tid >> 6, lane = tid & 63;
    for (int o = w5; o < 5; o += 4) {
        float a = 0.f;
        for (int d = lane; d < ND + HID; d += 64) a = fmaf(poolS[d], fcw[d * 5 + o], a);
        a = waveReduceSum(a);
        if (lane == 0) out[(size_t)(graph_base + g) * 5 + o] = a + fcb[o];
    }
}

// ============ launch ============
extern "C" void kernel_launch(void* const* d_in, const int* in_sizes, int n_in,
                              void* d_out, int out_size, void* d_ws, size_t ws_size,
                              hipStream_t stream) {
    const float* x   = (const float*)d_in[0];
    const float* tw  = (const float*)d_in[1];
    const float* tb  = (const float*)d_in[2];
    const float* wl1 = (const float*)d_in[3];
    const float* wr1 = (const float*)d_in[4];
    const float* at1 = (const float*)d_in[5];
    const float* b1  = (const float*)d_in[6];
    const float* wl2 = (const float*)d_in[7];
    const float* wr2 = (const float*)d_in[8];
    const float* at2 = (const float*)d_in[9];
    const float* b2  = (const float*)d_in[10];
    const float* fcw = (const float*)d_in[11];
    const float* fcb = (const float*)d_in[12];
    const int*   ei  = (const int*)d_in[13];
    float* out = (float*)d_out;

    char* ws = (char*)d_ws;
    bf16*  xp   = (bf16*)(ws + OFF_XPACK);
    bf16*  wp   = (bf16*)(ws + OFF_WPACK);
    bf16*  b1p  = (bf16*)(ws + OFF_B1);
    bf16*  b2p  = (bf16*)(ws + OFF_B2);
    bf16*  n32  = (bf16*)(ws + OFF_N32);
    float* pN   = (float*)(ws + OFF_PN);
    int*   csr  = (int*)(ws + OFF_CSR);

    // chunk buffers: xlr C*50176 B ; h1f C*12544 B ; scE C*1444 ; wN C*196
    const size_t perC = 50176 + 12544 + 1444 + 196;
    int C = 512;
    for (int cand : {2048, 1024, 512}) {
        if (OFF_CHUNK + (size_t)cand * perC <= ws_size) { C = cand; break; }
    }
    bf16*  xlr = (bf16*)(ws + OFF_CHUNK);
    bf16*  h1f = (bf16*)(ws + OFF_CHUNK + (size_t)C * 50176);
    float* scE = (float*)(ws + OFF_CHUNK + (size_t)C * (50176 + 12544));
    float* wNB = scE + (size_t)C * NE;
    int nchunks = BATCH / C;
    int MtC = C * NN / 16;

    k_pack_x<<<dim3(MT_X * KT_X * 64 / 256), dim3(256), 0, stream>>>(x, xp);
    k_pack_w<<<dim3(NB_W * NTB * KT_X * 64 / 256), dim3(256), 0, stream>>>(tw, wp);
    k_pack_g1<<<dim3(8), dim3(256), 0, stream>>>(wl1, wr1, b1p);
    k_pack_g2<<<dim3(64), dim3(256), 0, stream>>>(wl2, wr2, b2p);
    k_csr_par<<<dim3(1), dim3(128), 0, stream>>>(ei, csr);
    k_gemm_node<<<dim3(32, NB_W), dim3(256), 0, stream>>>(xp, wp, tb, n32);
    k_pool<<<dim3(BATCH / 8), dim3(256), 0, stream>>>(n32, pN);

    for (int c = 0; c < nchunks; ++c) {
        const bf16* n32c = n32 + (size_t)c * C * NN * 32;
        k_fuse1<<<dim3(C), dim3(512), 0, stream>>>(n32c, b1p, h1f, at1, b1, ei, csr);
        k_gemm_l2<<<dim3(MtC / 8, 4), dim3(256), 0, stream>>>(h1f, b2p, xlr);
        k_score2<<<dim3(C), dim3(384), 0, stream>>>(xlr, at2, ei, scE);
        k_softwn<<<dim3(C), dim3(64), 0, stream>>>(scE, csr, ei, wNB);
        k_poolfc<<<dim3(C), dim3(256), 0, stream>>>(xlr, wNB, pN, b2, fcw, fcb,
                                                    c * C, out);
    }
}

// Round 14
// 891.687 us; speedup vs baseline: 1.4159x; 1.0534x over previous
//
#include <hip/hip_runtime.h>
#include <hip/hip_bf16.h>

typedef __bf16 bf16;
typedef __attribute__((ext_vector_type(8))) __bf16 bf16x8;
typedef __attribute__((ext_vector_type(4))) __bf16 bf16x4;
typedef __attribute__((ext_vector_type(4))) float f32x4;
typedef __attribute__((ext_vector_type(2))) float f32x2;

constexpr int BATCH = 8192, NN = 49, ND = 26, NOUT = 1274, FD = 1280;
constexpr int HID = 256, NE = 361, HEADS = 4;
constexpr int KT_X = 40;
constexpr int MT_X = 512;
constexpr int NB_W = 10;
constexpr int NTB  = 9;

// ---- workspace layout (bytes) ----
constexpr size_t OFF_XPACK = 0;
constexpr size_t SZ_XPACK  = (size_t)MT_X * KT_X * 512 * 2;
constexpr size_t OFF_WPACK = OFF_XPACK + SZ_XPACK;
constexpr size_t SZ_WPACK  = (size_t)NB_W * NTB * KT_X * 512 * 2;
constexpr size_t OFF_B1    = OFF_WPACK + SZ_WPACK;
constexpr size_t SZ_B1     = (size_t)32 * 512 * 2;
constexpr size_t OFF_B2    = OFF_B1 + SZ_B1;
constexpr size_t SZ_B2     = (size_t)32 * 8 * 512 * 2;
constexpr size_t OFF_N32   = OFF_B2 + SZ_B2;
constexpr size_t SZ_N32    = (size_t)BATCH * NN * 32 * 2;
constexpr size_t OFF_PN    = OFF_N32 + SZ_N32;
constexpr size_t SZ_PN     = (size_t)BATCH * ND * 4;
constexpr size_t OFF_CSR   = OFF_PN + SZ_PN;
constexpr size_t SZ_CSR    = 8192;
constexpr size_t OFF_CHUNK = OFF_CSR + SZ_CSR;

// csr int layout: [0..49] in-off | [50..410] in-edge id | [411..771] in-edge src
//                 [772..821] out-off | [822..1182] out-edge id

// packed score accumulate: sa += a2*v, sb += a2*|v|, v = bf16(lo,hi of u) sums
static __device__ __forceinline__ void acc2(unsigned int uxl, unsigned int uxr,
                                            f32x2 a2, f32x2& sa, f32x2& sb) {
    f32x2 vl, vr;
    vl.x = __uint_as_float(uxl << 16);
    vl.y = __uint_as_float(uxl & 0xffff0000u);
    vr.x = __uint_as_float(uxr << 16);
    vr.y = __uint_as_float(uxr & 0xffff0000u);
    f32x2 v = vl + vr;
    f32x2 av;
    av.x = fabsf(v.x); av.y = fabsf(v.y);
    sa += a2 * v;
    sb += a2 * av;
}

// ============ K0a: pack x -> A-fragments bf16 ============
__global__ __launch_bounds__(256) void k_pack_x(const float* __restrict__ x,
                                                bf16* __restrict__ xp) {
    int g = blockIdx.x * 256 + threadIdx.x;
    int lane = g & 63, frag = g >> 6;
    int mt = frag / KT_X, kt = frag - mt * KT_X;
    int row = mt * 16 + (lane & 15);
    int k0  = kt * 32 + (lane >> 4) * 8;
    const float* src = x + (size_t)row * FD + k0;
    bf16x8 v;
#pragma unroll
    for (int j = 0; j < 8; ++j) v[j] = (bf16)src[j];
    *(bf16x8*)(xp + ((size_t)frag * 64 + lane) * 8) = v;
}

// ======== K0b: pack transform_w -> B-frags, node-aligned col-blocks ========
__global__ __launch_bounds__(256) void k_pack_w(const float* __restrict__ w,
                                                bf16* __restrict__ wp) {
    int g = blockIdx.x * 256 + threadIdx.x;
    int lane = g & 63, frag = g >> 6;
    int kt = frag % KT_X, t2 = frag / KT_X;
    int nt = t2 % NTB, nb = t2 / NTB;
    int col = nb * 130 + nt * 16 + (lane & 15);
    int k0  = kt * 32 + (lane >> 4) * 8;
    bool ok = (col < NOUT) && (col < nb * 130 + 130);
    bf16x8 v;
#pragma unroll
    for (int j = 0; j < 8; ++j)
        v[j] = ok ? (bf16)w[(size_t)(k0 + j) * NOUT + col] : (bf16)0.f;
    *(bf16x8*)(wp + ((size_t)frag * 64 + lane) * 8) = v;
}

// ============ K0c: pack g1 -> B-fragments ============
__global__ __launch_bounds__(256) void k_pack_g1(const float* __restrict__ wl,
                                                 const float* __restrict__ wr,
                                                 bf16* __restrict__ bp) {
    int g = blockIdx.x * 256 + threadIdx.x;
    int lane = g & 63, nt = g >> 6;
    int n  = nt * 16 + (lane & 15);
    int k0 = (lane >> 4) * 8;
    bf16x8 v;
#pragma unroll
    for (int j = 0; j < 8; ++j) {
        int k = k0 + j;
        float f = 0.f;
        if (k < ND) f = (n < HID) ? wl[k * HID + n] : wr[k * HID + (n - HID)];
        v[j] = (bf16)f;
    }
    *(bf16x8*)(bp + ((size_t)nt * 64 + lane) * 8) = v;
}

// ============ K0d: pack g2 -> B-fragments ============
__global__ __launch_bounds__(256) void k_pack_g2(const float* __restrict__ wl,
                                                 const float* __restrict__ wr,
                                                 bf16* __restrict__ bp) {
    int g = blockIdx.x * 256 + threadIdx.x;
    int lane = g & 63, frag = g >> 6;
    int nt = frag >> 3, kt = frag & 7;
    int n  = nt * 16 + (lane & 15);
    int k0 = kt * 32 + (lane >> 4) * 8;
    bf16x8 v;
#pragma unroll
    for (int j = 0; j < 8; ++j) {
        int k = k0 + j;
        float f = (n < HID) ? wl[k * HID + n] : wr[k * HID + (n - HID)];
        v[j] = (bf16)f;
    }
    *(bf16x8*)(bp + ((size_t)frag * 64 + lane) * 8) = v;
}

// ============ K0e: build in/out CSR (parallel, deterministic) ============
__global__ __launch_bounds__(128) void k_csr_par(const int* __restrict__ ei,
                                                 int* __restrict__ csr) {
    __shared__ int es[NE], ed[NE], cnt[NN], ocnt[NN], off[NN + 1], ooff[NN + 1];
    int tid = threadIdx.x;
    if (tid < NN) { cnt[tid] = 0; ocnt[tid] = 0; }
    for (int e = tid; e < NE; e += 128) { es[e] = ei[e]; ed[e] = ei[NE + e]; }
    __syncthreads();
    for (int e = tid; e < NE; e += 128) {
        atomicAdd(&cnt[ed[e]], 1);
        atomicAdd(&ocnt[es[e]], 1);
    }
    __syncthreads();
    if (tid == 0) {
        off[0] = 0; ooff[0] = 0;
        for (int n = 0; n < NN; ++n) {
            off[n + 1] = off[n] + cnt[n];
            ooff[n + 1] = ooff[n] + ocnt[n];
        }
    }
    __syncthreads();
    if (tid < NN) {
        int p = off[tid];
        for (int e = 0; e < NE; ++e)
            if (ed[e] == tid) { csr[50 + p] = e; csr[411 + p] = es[e]; ++p; }
    } else if (tid >= 64 && tid < 64 + NN) {
        int n = tid - 64;
        int p = ooff[n];
        for (int e = 0; e < NE; ++e)
            if (es[e] == n) { csr[822 + p] = e; ++p; }
    }
    if (tid < 50) { csr[tid] = off[tid]; csr[772 + tid] = ooff[tid]; }
}

// ==== K1: transform GEMM -> node32 [B*49][32] bf16 (4 Mt/wave) ====
__global__ __launch_bounds__(256, 2) void k_gemm_node(const bf16* __restrict__ xp,
                                                      const bf16* __restrict__ wp,
                                                      const float* __restrict__ tb,
                                                      bf16* __restrict__ node32) {
    __shared__ bf16 L[128][148];
    __shared__ float tbS[144];
    int tid = threadIdx.x, lane = tid & 63, w = tid >> 6;
    int nb = blockIdx.y, C0 = nb * 130;
    int mt0 = blockIdx.x * 16 + w * 4;
    if (tid < 144) { int col = C0 + tid; tbS[tid] = (col < NOUT) ? tb[col] : 0.f; }
    f32x4 acc[4][9] = {};
    const bf16* wpB = wp + (size_t)(nb * NTB) * KT_X * 512;
    for (int kt = 0; kt < KT_X; ++kt) {
        bf16x8 a[4];
#pragma unroll
        for (int i = 0; i < 4; ++i)
            a[i] = *(const bf16x8*)(xp + (((size_t)(mt0 + i) * KT_X + kt) * 64 + lane) * 8);
#pragma unroll
        for (int j = 0; j < NTB; ++j) {
            bf16x8 b = *(const bf16x8*)(wpB + ((size_t)(j * KT_X + kt) * 64 + lane) * 8);
#pragma unroll
            for (int i = 0; i < 4; ++i)
                acc[i][j] = __builtin_amdgcn_mfma_f32_16x16x32_bf16(a[i], b, acc[i][j], 0, 0, 0);
        }
    }
    int c0 = lane & 15, r0 = (lane >> 4) * 4;
    int nodes = (nb == 9) ? 4 : 5;
    int total = 128 * nodes * 4;
    for (int half = 0; half < 2; ++half) {
        __syncthreads();
        if ((w >> 1) == half) {
            int lrbase = (w & 1) * 64;
#pragma unroll
            for (int i = 0; i < 4; ++i) {
#pragma unroll
                for (int j = 0; j < NTB; ++j) {
                    int col = j * 16 + c0;
                    float bias = tbS[col];
#pragma unroll
                    for (int r = 0; r < 4; ++r)
                        L[lrbase + i * 16 + r0 + r][col] = (bf16)(acc[i][j][r] + bias);
                }
            }
        }
        __syncthreads();
        int B0 = blockIdx.x * 256 + half * 128;
        for (int t = tid; t < total; t += 256) {
            int q = t & 3, t2 = t >> 2;
            int n_l = t2 % nodes, brow = t2 / nodes;
            bf16x8 o;
#pragma unroll
            for (int jj = 0; jj < 8; ++jj) {
                int d = q * 8 + jj;
                o[jj] = (d < ND) ? L[brow][n_l * 26 + d] : (bf16)0.f;
            }
            *(bf16x8*)(node32 + (((size_t)(B0 + brow) * NN + nb * 5 + n_l) * 32 + q * 8)) = o;
        }
    }
}

// ============ K1b: pooled node features (sum over 49 nodes) ============
__global__ __launch_bounds__(256) void k_pool(const bf16* __restrict__ node32,
                                              float* __restrict__ pN) {
    int b = blockIdx.x * 8 + (threadIdx.x >> 5);
    int d = threadIdx.x & 31;
    if (d >= ND) return;
    const bf16* base = node32 + (size_t)b * NN * 32 + d;
    float s = 0.f;
    for (int n = 0; n < NN; ++n) s += (float)base[n * 32];
    pN[b * ND + d] = s;
}

// ======= K_A: fused layer-1 GEMM (swapped-mfma epilogue) + edge phase 1 ====
__global__ __launch_bounds__(512, 2) void k_fuse1(const bf16* __restrict__ n32,
                                                  const bf16* __restrict__ B1p,
                                                  bf16* __restrict__ h1f,
                                                  const float* __restrict__ att1,
                                                  const float* __restrict__ g1b,
                                                  const int* __restrict__ ei,
                                                  const int* __restrict__ csr) {
    __shared__ __align__(16) char X[NN * 1024];
    __shared__ __align__(16) float attS[256];
    __shared__ float sc[NE * 4], srden[NN * 4], bS[256];
    __shared__ int ieOff[50], ieId[NE], ieSrc[NE], srcS[NE], dstS[NE];

    int tid = threadIdx.x, lane = tid & 63, w = tid >> 6, g = blockIdx.x;

    for (int i = tid; i < 256; i += 512) { attS[i] = att1[i]; bS[i] = g1b[i]; }
    for (int i = tid; i < NE; i += 512) {
        srcS[i] = ei[i]; dstS[i] = ei[NE + i];
        ieId[i] = csr[50 + i]; ieSrc[i] = csr[411 + i];
    }
    if (tid < 50) ieOff[tid] = csr[tid];

    // ---- layer-1 GEMM: mfma(Wfrag as A, nodefrag as B) -> X swizzled ----
    {
        int mt = w & 3, ng = w >> 2;
        int m = mt * 16 + (lane & 15);
        bf16x8 bfrag = {};
        if (m < NN)
            bfrag = *(const bf16x8*)(n32 + ((size_t)(g * NN + m) * 32 + (lane >> 4) * 8));
        int chq = (lane >> 4) * 4;
        int sw = (m & 7) << 4;
        char* rowp = X + m * 1024;
#pragma unroll
        for (int j = 0; j < 16; ++j) {
            f32x4 z = {0.f, 0.f, 0.f, 0.f};
            bf16x8 afrag = *(const bf16x8*)(B1p + ((size_t)(ng * 16 + j) * 64 + lane) * 8);
            f32x4 acc = __builtin_amdgcn_mfma_f32_16x16x32_bf16(afrag, bfrag, z, 0, 0, 0);
            if (m < NN) {
                int ch = (ng * 16 + j) * 16 + chq;
                bf16x4 o4;
#pragma unroll
                for (int r = 0; r < 4; ++r) o4[r] = (bf16)acc[r];
                *(bf16x4*)(rowp + ((ch * 2) ^ sw)) = o4;
            }
        }
    }
    __syncthreads();

    // ---- scores: bank-uniform slots + packed-fp32 factored lrelu ----
    int lrot = tid & 7;
    for (int task = tid; task < NE * 4; task += 512) {
        int h = task / NE, e = task - h * NE;
        int s = srcS[e], d = dstS[e];
        int s7 = s & 7;
        int sws = s7 << 4, swd = (d & 7) << 4;
        const char* ps = X + s * 1024;
        const char* pd = X + d * 1024;
        f32x2 saA = {0.f, 0.f}, saB = {0.f, 0.f};
        f32x2 sbA = {0.f, 0.f}, sbB = {0.f, 0.f};
#pragma unroll
        for (int i = 0; i < 8; ++i) {
            int cc = (((i + lrot) & 7) ^ s7) * 8;
            uint4 uxl = *(const uint4*)(ps + (((h * 64 + cc) * 2) ^ sws));
            uint4 uxr = *(const uint4*)(pd + (((256 + h * 64 + cc) * 2) ^ swd));
            const f32x2* at = (const f32x2*)(attS + h * 64 + cc);
            acc2(uxl.x, uxr.x, at[0], saA, sbA);
            acc2(uxl.y, uxr.y, at[1], saB, sbB);
            acc2(uxl.z, uxr.z, at[2], saA, sbA);
            acc2(uxl.w, uxr.w, at[3], saB, sbB);
        }
        f32x2 sa = saA + saB, sb = sbA + sbB;
        sc[e * 4 + h] = 0.6f * (sa.x + sa.y) + 0.4f * (sb.x + sb.y);
    }
    __syncthreads();
    for (int t = tid; t < NN * 4; t += 512) {
        int n = t >> 2, h = t & 3;
        float m = -1e30f;
        for (int j = ieOff[n]; j < ieOff[n + 1]; ++j) m = fmaxf(m, sc[ieId[j] * 4 + h]);
        float den = 0.f;
        for (int j = ieOff[n]; j < ieOff[n + 1]; ++j) {
            int idx = ieId[j] * 4 + h;
            float ex = __expf(sc[idx] - m);
            sc[idx] = ex; den += ex;
        }
        srden[t] = 1.f / den;
    }
    __syncthreads();
    for (int task = tid; task < NN * 32; task += 512) {
        int n = task >> 5, cb = task & 31;
        int ch0 = cb * 8, hh = cb >> 3;
        float a8[8] = {};
        int j0 = ieOff[n], j1 = ieOff[n + 1];
        for (int j = j0; j < j1; ++j) {
            float al = sc[ieId[j] * 4 + hh];
            int s = ieSrc[j];
            bf16x8 xv = *(const bf16x8*)(X + s * 1024 + ((ch0 * 2) ^ ((s & 7) << 4)));
#pragma unroll
            for (int q = 0; q < 8; ++q) a8[q] = fmaf(al, (float)xv[q], a8[q]);
        }
        float rs = srden[n * 4 + hh];
        bf16x8 o;
#pragma unroll
        for (int q = 0; q < 8; ++q) {
            float v = fmaf(a8[q], rs, bS[ch0 + q]);
            v = v > 0.f ? v : (__expf(v) - 1.f);
            o[q] = (bf16)v;
        }
        int Rl = g * NN + n;
        int kt = ch0 >> 5, kg = (ch0 >> 3) & 3;
        size_t addr = (((size_t)(Rl >> 4) * 8 + kt) * 64 + (Rl & 15) + 16 * kg) * 8;
        *(bf16x8*)(h1f + addr) = o;
    }
}

// ==== K_B1: batched layer-2 GEMM (h1 frags -> LINEAR row-major xlr) ========
__global__ __launch_bounds__(256) void k_gemm_l2(const bf16* __restrict__ Af,
                                                 const bf16* __restrict__ Bf,
                                                 bf16* __restrict__ xlr) {
    __shared__ bf16 LT[128][136];
    int tid = threadIdx.x, lane = tid & 63, w = tid >> 6;
    int mtb = blockIdx.x * 8 + (w >> 1) * 4;
    int ntb = blockIdx.y * 8 + (w & 1) * 4;
    f32x4 acc[4][4] = {};
    for (int kt = 0; kt < 8; ++kt) {
        bf16x8 a[4], b[4];
#pragma unroll
        for (int i = 0; i < 4; ++i)
            a[i] = *(const bf16x8*)(Af + (((size_t)(mtb + i) * 8 + kt) * 64 + lane) * 8);
#pragma unroll
        for (int j = 0; j < 4; ++j)
            b[j] = *(const bf16x8*)(Bf + (((size_t)(ntb + j) * 8 + kt) * 64 + lane) * 8);
#pragma unroll
        for (int i = 0; i < 4; ++i)
#pragma unroll
            for (int j = 0; j < 4; ++j)
                acc[i][j] = __builtin_amdgcn_mfma_f32_16x16x32_bf16(a[i], b[j], acc[i][j], 0, 0, 0);
    }
    int c0 = lane & 15, r0 = (lane >> 4) * 4;
    int lr0 = (w >> 1) * 64, lc0 = (w & 1) * 64;
#pragma unroll
    for (int i = 0; i < 4; ++i)
#pragma unroll
        for (int j = 0; j < 4; ++j)
#pragma unroll
            for (int r = 0; r < 4; ++r)
                LT[lr0 + i * 16 + r0 + r][lc0 + j * 16 + c0] = (bf16)acc[i][j][r];
    __syncthreads();
    size_t R0 = (size_t)blockIdx.x * 128, C0 = (size_t)blockIdx.y * 128;
#pragma unroll
    for (int it = 0; it < 8; ++it) {
        int idx = (it * 256 + tid) * 8;
        int r = idx >> 7, c = idx & 127;
        bf16x8 v = *(const bf16x8*)&LT[r][c];
        *(bf16x8*)(xlr + (R0 + r) * 512 + C0 + c) = v;
    }
}

// ====== K_B2a: layer-2 edge scores, X staged ONCE in LDS (block/graph) =====
__global__ __launch_bounds__(384) void k_score2(const bf16* __restrict__ xlr,
                                                const float* __restrict__ att2,
                                                const int* __restrict__ ei,
                                                float* __restrict__ scE) {
    __shared__ __align__(16) char X[NN * 1024];
    __shared__ float attS[256];
    int tid = threadIdx.x, g = blockIdx.x;
    const char* srcp = (const char*)(xlr + (size_t)g * NN * 512);
    for (int off = tid * 16; off < NN * 1024; off += 384 * 16) {
        int row = off >> 10;
        *(uint4*)(X + (off ^ ((row & 7) << 4))) = *(const uint4*)(srcp + off);
    }
    if (tid < 256) attS[tid] = att2[tid];
    __syncthreads();
    if (tid >= NE) return;
    int s = ei[tid], d = ei[NE + tid];
    int s7 = s & 7;
    int sws = s7 << 4, swd = (d & 7) << 4;
    const char* ps = X + s * 1024;
    const char* pd = X + d * 1024;
    int rot = tid & 7;
    f32x2 saA = {0.f, 0.f}, saB = {0.f, 0.f};
    f32x2 sbA = {0.f, 0.f}, sbB = {0.f, 0.f};
#pragma unroll 8
    for (int i = 0; i < 32; ++i) {
        int jb = (i + rot) & 31;
        int cc = ((jb & ~7) | ((jb & 7) ^ s7)) * 8;   // stored xl slot uniform
        uint4 uxl = *(const uint4*)(ps + ((cc * 2) ^ sws));
        uint4 uxr = *(const uint4*)(pd + (((256 + cc) * 2) ^ swd));
        const f32x2* at = (const f32x2*)(attS + cc);
        acc2(uxl.x, uxr.x, at[0], saA, sbA);
        acc2(uxl.y, uxr.y, at[1], saB, sbB);
        acc2(uxl.z, uxr.z, at[2], saA, sbA);
        acc2(uxl.w, uxr.w, at[3], saB, sbB);
    }
    f32x2 sa = saA + saB, sb = sbA + sbB;
    scE[(size_t)g * NE + tid] = 0.6f * (sa.x + sa.y) + 0.4f * (sb.x + sb.y);
}

// ====== K_B2b: per-graph softmax stats + out-node weights (64 thr) =========
__global__ __launch_bounds__(64) void k_softwn(const float* __restrict__ scE,
                                               const int* __restrict__ csr,
                                               const int* __restrict__ ei,
                                               float* __restrict__ wN) {
    __shared__ float sm[NN], sr[NN];
    int g = blockIdx.x, tid = threadIdx.x;
    const float* sg = scE + (size_t)g * NE;
    if (tid < NN) {
        int j0 = csr[tid], j1 = csr[tid + 1];
        float m = -1e30f;
        for (int j = j0; j < j1; ++j) m = fmaxf(m, sg[csr[50 + j]]);
        float den = 0.f;
        for (int j = j0; j < j1; ++j) den += __expf(sg[csr[50 + j]] - m);
        sm[tid] = m; sr[tid] = 1.f / den;
    }
    __syncthreads();
    if (tid < NN) {
        float wa = 0.f;
        int j0 = csr[772 + tid], j1 = csr[772 + tid + 1];
        for (int j = j0; j < j1; ++j) {
            int e = csr[822 + j];
            int d = ei[NE + e];
            wa += __expf(sg[e] - sm[d]) * sr[d];
        }
        wN[(size_t)g * NN + tid] = wa;
    }
}

// ============ K_B2d: pooled g + FC (block per graph, lean LDS) ============
static __device__ __forceinline__ float waveReduceSum(float v) {
#pragma unroll
    for (int m = 32; m > 0; m >>= 1) v += __shfl_xor(v, m, 64);
    return v;
}

__global__ __launch_bounds__(256) void k_poolfc(const bf16* __restrict__ xlr,
                                                const float* __restrict__ wN,
                                                const float* __restrict__ pN,
                                                const float* __restrict__ g2b,
                                                const float* __restrict__ fcw,
                                                const float* __restrict__ fcb,
                                                int graph_base,
                                                float* __restrict__ out) {
    __shared__ float wSs[NN];
    __shared__ float poolS[288];
    int tid = threadIdx.x, g = blockIdx.x;
    if (tid < NN) wSs[tid] = wN[(size_t)g * NN + tid];
    if (tid >= 64 && tid < 64 + ND)
        poolS[tid - 64] = pN[(size_t)(graph_base + g) * ND + (tid - 64)] * (1.f / NN);
    __syncthreads();
    {
        const bf16* base = xlr + (size_t)g * NN * 512 + tid;
        float acc = 0.f;
        for (int n = 0; n < NN; ++n) acc = fmaf(wSs[n], (float)base[n * 512], acc);
        poolS[ND + tid] = acc * (1.f / NN) + g2b[tid];
    }
    __syncthreads();
    int w5 = tid >> 6, lane = tid & 63;
    for (int o = w5; o < 5; o += 4) {
        float a = 0.f;
        for (int d = lane; d < ND + HID; d += 64) a = fmaf(poolS[d], fcw[d * 5 + o], a);
        a = waveReduceSum(a);
        if (lane == 0) out[(size_t)(graph_base + g) * 5 + o] = a + fcb[o];
    }
}

// ============ launch ============
extern "C" void kernel_launch(void* const* d_in, const int* in_sizes, int n_in,
                              void* d_out, int out_size, void* d_ws, size_t ws_size,
                              hipStream_t stream) {
    const float* x   = (const float*)d_in[0];
    const float* tw  = (const float*)d_in[1];
    const float* tb  = (const float*)d_in[2];
    const float* wl1 = (const float*)d_in[3];
    const float* wr1 = (const float*)d_in[4];
    const float* at1 = (const float*)d_in[5];
    const float* b1  = (const float*)d_in[6];
    const float* wl2 = (const float*)d_in[7];
    const float* wr2 = (const float*)d_in[8];
    const float* at2 = (const float*)d_in[9];
    const float* b2  = (const float*)d_in[10];
    const float* fcw = (const float*)d_in[11];
    const float* fcb = (const float*)d_in[12];
    const int*   ei  = (const int*)d_in[13];
    float* out = (float*)d_out;

    char* ws = (char*)d_ws;
    bf16*  xp   = (bf16*)(ws + OFF_XPACK);
    bf16*  wp   = (bf16*)(ws + OFF_WPACK);
    bf16*  b1p  = (bf16*)(ws + OFF_B1);
    bf16*  b2p  = (bf16*)(ws + OFF_B2);
    bf16*  n32  = (bf16*)(ws + OFF_N32);
    float* pN   = (float*)(ws + OFF_PN);
    int*   csr  = (int*)(ws + OFF_CSR);

    // chunk buffers: xlr C*50176 B ; h1f C*12544 B ; scE C*1444 ; wN C*196
    const size_t perC = 50176 + 12544 + 1444 + 196;
    int C = 512;
    for (int cand : {2048, 1024, 512}) {
        if (OFF_CHUNK + (size_t)cand * perC <= ws_size) { C = cand; break; }
    }
    bf16*  xlr = (bf16*)(ws + OFF_CHUNK);
    bf16*  h1f = (bf16*)(ws + OFF_CHUNK + (size_t)C * 50176);
    float* scE = (float*)(ws + OFF_CHUNK + (size_t)C * (50176 + 12544));
    float* wNB = scE + (size_t)C * NE;
    int nchunks = BATCH / C;
    int MtC = C * NN / 16;

    k_pack_x<<<dim3(MT_X * KT_X * 64 / 256), dim3(256), 0, stream>>>(x, xp);
    k_pack_w<<<dim3(NB_W * NTB * KT_X * 64 / 256), dim3(256), 0, stream>>>(tw, wp);
    k_pack_g1<<<dim3(8), dim3(256), 0, stream>>>(wl1, wr1, b1p);
    k_pack_g2<<<dim3(64), dim3(256), 0, stream>>>(wl2, wr2, b2p);
    k_csr_par<<<dim3(1), dim3(128), 0, stream>>>(ei, csr);
    k_gemm_node<<<dim3(32, NB_W), dim3(256), 0, stream>>>(xp, wp, tb, n32);
    k_pool<<<dim3(BATCH / 8), dim3(256), 0, stream>>>(n32, pN);

    for (int c = 0; c < nchunks; ++c) {
        const bf16* n32c = n32 + (size_t)c * C * NN * 32;
        k_fuse1<<<dim3(C), dim3(512), 0, stream>>>(n32c, b1p, h1f, at1, b1, ei, csr);
        k_gemm_l2<<<dim3(MtC / 8, 4), dim3(256), 0, stream>>>(h1f, b2p, xlr);
        k_score2<<<dim3(C), dim3(384), 0, stream>>>(xlr, at2, ei, scE);
        k_softwn<<<dim3(C), dim3(64), 0, stream>>>(scE, csr, ei, wNB);
        k_poolfc<<<dim3(C), dim3(256), 0, stream>>>(xlr, wNB, pN, b2, fcw, fcb,
                                                    c * C, out);
    }
}